// Round 13
// baseline (1122.003 us; speedup 1.0000x reference)
//
#include <hip/hip_runtime.h>
#include <cstdint>
#include <cstddef>

typedef unsigned short u16;
typedef __attribute__((__ext_vector_type__(8))) __bf16 bf16x8;
typedef __attribute__((__ext_vector_type__(4))) float f32x4;
typedef __attribute__((__ext_vector_type__(8))) unsigned short u16x8;

#define DEVI __device__ __forceinline__

constexpr int Bb = 2, Ss = 1024, Dd = 1024, Hh = 16;
constexpr int Mm = Bb * Ss;
constexpr int QKD = 128;
constexpr float EPSF = 1.1920929e-07f;
constexpr float NEG = -1e30f;
constexpr float QSCALE = 0.10206207261596577f; // 1/sqrt(96)
constexpr float LOG1E4_16 = 9.210340371976184f / 16.f;

DEVI u16 f2b(float f) {
  union { float f; uint32_t u; } a; a.f = f;
  uint32_t r = a.u + 0x7FFFu + ((a.u >> 16) & 1u);
  return (u16)(r >> 16);
}
DEVI float b2f(u16 h) {
  union { uint32_t u; float f; } a; a.u = ((uint32_t)h) << 16; return a.f;
}

// ---------------- batched fp32 -> bf16 transposed weight conversion
struct WJob { const float* src; u16* dst; int K; int N; int perm; int ntiles; };
struct WJobs { WJob j[7]; };

__global__ __launch_bounds__(256) void k_wcvt_batch(WJobs jobs, int njobs) {
  int t = blockIdx.x;
  int ji = 0;
  while (ji < njobs - 1 && t >= jobs.j[ji].ntiles) { t -= jobs.j[ji].ntiles; ++ji; }
  const float* __restrict__ src = jobs.j[ji].src;
  u16* __restrict__ dst = jobs.j[ji].dst;
  const int K = jobs.j[ji].K, N = jobs.j[ji].N, perm = jobs.j[ji].perm;
  const int ktiles = K >> 6;
  const int bk = (t % ktiles) * 64;
  const int bn = (t / ktiles) * 64;
  __shared__ float ts[64][65];
  const int tid = threadIdx.x;
  {
    int c4 = tid & 15, r = tid >> 4;
    #pragma unroll
    for (int p = 0; p < 4; ++p) {
      int row = r + p * 16;
      int col = bn + c4 * 4;
      float4 v = make_float4(0.f, 0.f, 0.f, 0.f);
      if (col < N) v = *(const float4*)(src + (size_t)(bk + row) * N + col);
      ts[row][c4 * 4 + 0] = v.x; ts[row][c4 * 4 + 1] = v.y;
      ts[row][c4 * 4 + 2] = v.z; ts[row][c4 * 4 + 3] = v.w;
    }
  }
  __syncthreads();
  {
    int k8 = tid & 7, c = tid >> 3;
    #pragma unroll
    for (int p = 0; p < 2; ++p) {
      int cc = c + p * 32;
      int gcol = bn + cc;
      int row = perm ? ((gcol < 2816) ? (gcol * 2) : ((gcol - 2816) * 2 + 1)) : gcol;
      u16x8 o;
      #pragma unroll
      for (int q = 0; q < 8; ++q) o[q] = f2b(ts[k8 * 8 + q][cc]);
      *(u16x8*)(dst + (size_t)row * K + bk + k8 * 8) = o;
    }
  }
}

// ---------------- embedding gather
__global__ void k_embed(const int* __restrict__ tok, const float* __restrict__ emb,
                        float* __restrict__ h) {
  int m = blockIdx.x;
  int t = tok[m];
  const float4* src = (const float4*)(emb + (size_t)t * Dd);
  float4* dst = (float4*)(h + (size_t)m * Dd);
  dst[threadIdx.x] = src[threadIdx.x];
}

// ---------------- rmsnorm: f32 (stride inStride) -> bf16 (stride K)
__global__ void k_rms(const float* __restrict__ in, int inStride,
                      const float* __restrict__ w, u16* __restrict__ out, int K) {
  int m = blockIdx.x;
  const float* x = in + (size_t)m * inStride;
  float ss = 0.f;
  for (int i = threadIdx.x; i < K; i += 256) { float v = x[i]; ss += v * v; }
  #pragma unroll
  for (int off = 32; off; off >>= 1) ss += __shfl_xor(ss, off);
  __shared__ float red[4];
  if ((threadIdx.x & 63) == 0) red[threadIdx.x >> 6] = ss;
  __syncthreads();
  float r = rsqrtf((red[0] + red[1] + red[2] + red[3]) / (float)K + EPSF);
  for (int i = threadIdx.x; i < K; i += 256)
    out[(size_t)m * K + i] = f2b(x[i] * r * w[i]);
}

// ---------------- build Q and K (rope cols 64..95; Q scaled; pad to 128)
// qf is bf16 now (written by MODE-2 GEMM).
__global__ void k_buildqk(const u16* __restrict__ qf, const u16* __restrict__ kv,
                          const float* __restrict__ ckvq, u16* __restrict__ Q,
                          u16* __restrict__ Kb) {
  int s = blockIdx.x, bh = blockIdx.y;
  int b = bh >> 4, h = bh & 15;
  int d = threadIdx.x;
  int m = b * Ss + s;
  int j = d - 64;
  float sn = 0.f, cs = 0.f;
  if (d >= 64 && d < 96) {
    float theta = __expf(-(float)(j & 15) * LOG1E4_16);
    __sincosf((float)s * theta, &sn, &cs);
  }
  const u16* qrow = qf + (size_t)m * (Hh * 96) + h * 96;
  float qv = 0.f;
  if (d < 64) qv = b2f(qrow[d]);
  else if (d < 96) {
    float x = b2f(qrow[64 + j]), o = b2f(qrow[64 + (j ^ 16)]);
    qv = x * cs + ((j < 16) ? -o : o) * sn;
  }
  Q[((size_t)bh * Ss + s) * QKD + d] = f2b(qv * QSCALE);
  u16 kvv = 0;
  if (d < 64) kvv = kv[(size_t)m * 2048 + h * 128 + d];
  else if (d < 96) {
    const float* rr = ckvq + (size_t)m * 768 + 256;
    float x = rr[j], o = rr[j ^ 16];
    kvv = f2b(x * cs + ((j < 16) ? -o : o) * sn);
  }
  Kb[((size_t)bh * Ss + s) * QKD + d] = kvv;
}

// ---------------- build V^T (per head: [64][1024]), bf16 in -> bf16 out
__global__ void k_buildvt(const u16* __restrict__ kv, u16* __restrict__ Vt) {
  __shared__ u16 t[32][33];
  int bh = blockIdx.x, s0 = blockIdx.y * 32, d0 = blockIdx.z * 32;
  int b = bh >> 4, h = bh & 15;
  int tx = threadIdx.x, ty = threadIdx.y;
  #pragma unroll
  for (int i = ty; i < 32; i += 8) {
    int s = s0 + i, d = d0 + tx;
    t[i][tx] = kv[(size_t)(b * Ss + s) * 2048 + h * 128 + 64 + d];
  }
  __syncthreads();
  #pragma unroll
  for (int i = ty; i < 32; i += 8) {
    int d = d0 + i, s = s0 + tx;
    Vt[((size_t)bh * 64 + d) * Ss + s] = t[tx][i];
  }
}

#define GAS __attribute__((address_space(1)))
#define LAS __attribute__((address_space(3)))
DEVI void gll16(const void* g, void* l) {
  __builtin_amdgcn_global_load_lds((GAS const void*)g, (LAS void*)l, 16, 0, 0);
}
#define VMW(n) asm volatile("s_waitcnt vmcnt(" #n ")" ::: "memory")
#define FENCE asm volatile("" ::: "memory")

// ---------------- fused flash attention (causal), bf16 in/out
__global__ __launch_bounds__(256) void k_flash(
    const u16* __restrict__ Qg, const u16* __restrict__ Kg,
    const u16* __restrict__ Vtg, u16* __restrict__ attn) {
  __shared__ u16 lK[2][64 * 128];
  __shared__ u16 lV[2][64 * 64];
  __shared__ u16 lP[4][16 * 64];
  const int tid = threadIdx.x;
  const int qt = blockIdx.x, bh = blockIdx.y;
  const int b = bh >> 4, h = bh & 15;
  const int lane = tid & 63, w = tid >> 6;
  const int g = lane >> 4, fr = lane & 15;
  const u16* Qh = Qg + (size_t)bh * Ss * QKD;
  const u16* Kh = Kg + (size_t)bh * Ss * QKD;
  const u16* Vh = Vtg + (size_t)bh * 64 * Ss;

  auto stageKV = [&](int buf, int kt) {
    int r = tid >> 4, c = tid & 15;
    #pragma unroll
    for (int gg = 0; gg < 4; ++gg) {
      int row = gg * 16 + r;
      const u16* src = Kh + (size_t)(kt * 64 + row) * QKD + ((c ^ (row & 7)) * 8);
      gll16(src, (u16*)lK[buf] + gg * 2048 + tid * 8);
    }
    int r2 = tid >> 3, c2 = tid & 7;
    #pragma unroll
    for (int gg = 0; gg < 2; ++gg) {
      int d = gg * 32 + r2;
      const u16* src = Vh + (size_t)d * Ss + kt * 64 + ((c2 ^ (d & 7)) * 8);
      gll16(src, (u16*)lV[buf] + gg * 2048 + tid * 8);
    }
  };

  const int q0 = qt * 64;
  bf16x8 af[4];
  const u16* qrow = Qh + (size_t)(q0 + w * 16 + fr) * QKD + g * 8;
  #pragma unroll
  for (int k4 = 0; k4 < 4; ++k4) af[k4] = *(const bf16x8*)(qrow + k4 * 32);

  f32x4 acc_o[4] = {};
  float mrow = NEG, lrow = 0.f;

  stageKV(0, 0);

  for (int kt = 0; kt <= qt; ++kt) {
    const int cur = kt & 1;
    if (kt < qt) { stageKV(cur ^ 1, kt + 1); VMW(6); }
    else { VMW(0); }
    __builtin_amdgcn_s_barrier();
    FENCE;

    f32x4 accs[4] = {};
    #pragma unroll
    for (int j = 0; j < 4; ++j) {
      #pragma unroll
      for (int k4 = 0; k4 < 4; ++k4) {
        int row = j * 16 + fr;
        int ch = (k4 * 4 + g) ^ (row & 7);
        bf16x8 kf = *(const bf16x8*)&lK[cur][row * 128 + ch * 8];
        accs[j] = __builtin_amdgcn_mfma_f32_16x16x32_bf16(kf, af[k4], accs[j], 0, 0, 0);
      }
    }

    float p[16];
    float tmax = NEG;
    #pragma unroll
    for (int j = 0; j < 4; ++j)
      #pragma unroll
      for (int r = 0; r < 4; ++r) {
        float s = accs[j][r];
        int kloc = j * 16 + 4 * g + r;
        bool valid = (kt < qt) || (kloc <= w * 16 + fr);
        s = valid ? s : NEG;
        p[j * 4 + r] = s;
        tmax = fmaxf(tmax, s);
      }
    tmax = fmaxf(tmax, __shfl_xor(tmax, 16));
    tmax = fmaxf(tmax, __shfl_xor(tmax, 32));
    float mnew = fmaxf(mrow, tmax);
    float scale = __expf(mrow - mnew);
    float tsum = 0.f;
    #pragma unroll
    for (int i = 0; i < 16; ++i) { p[i] = __expf(p[i] - mnew); tsum += p[i]; }
    tsum += __shfl_xor(tsum, 16);
    tsum += __shfl_xor(tsum, 32);
    lrow = lrow * scale + tsum;
    mrow = mnew;

    #pragma unroll
    for (int j = 0; j < 4; ++j)
      #pragma unroll
      for (int t = 0; t < 2; ++t) {
        uint32_t u = (uint32_t)f2b(p[j * 4 + 2 * t]) |
                     ((uint32_t)f2b(p[j * 4 + 2 * t + 1]) << 16);
        int kp = 8 * j + 2 * g + t;
        int ch = kp >> 2, wi = kp & 3;
        ((uint32_t*)lP[w])[fr * 32 + ((ch ^ (fr & 7)) << 2) + wi] = u;
      }

    float sc_q[4];
    #pragma unroll
    for (int r = 0; r < 4; ++r) sc_q[r] = __shfl(scale, 4 * g + r);
    #pragma unroll
    for (int j2 = 0; j2 < 4; ++j2)
      #pragma unroll
      for (int r = 0; r < 4; ++r) acc_o[j2][r] *= sc_q[r];

    #pragma unroll
    for (int ksub = 0; ksub < 2; ++ksub) {
      int chp = (4 * ksub + g) ^ (fr & 7);
      bf16x8 pa = *(const bf16x8*)&((const u16*)lP[w])[fr * 64 + chp * 8];
      #pragma unroll
      for (int j2 = 0; j2 < 4; ++j2) {
        int d = j2 * 16 + fr;
        int chv = (ksub * 4 + g) ^ (d & 7);
        bf16x8 vf = *(const bf16x8*)&lV[cur][d * 64 + chv * 8];
        acc_o[j2] = __builtin_amdgcn_mfma_f32_16x16x32_bf16(pa, vf, acc_o[j2], 0, 0, 0);
      }
    }
    FENCE;
    __builtin_amdgcn_s_barrier();
    FENCE;
  }

  float li[4];
  #pragma unroll
  for (int r = 0; r < 4; ++r) li[r] = 1.f / __shfl(lrow, 4 * g + r);
  #pragma unroll
  for (int j2 = 0; j2 < 4; ++j2)
    #pragma unroll
    for (int r = 0; r < 4; ++r) {
      int q = q0 + w * 16 + 4 * g + r;
      int d = j2 * 16 + fr;
      attn[((size_t)(b * Ss) + q) * Dd + h * 64 + d] = f2b(acc_o[j2][r] * li[r]);
    }
}

// ---------------- generic bf16 MFMA GEMM, BMxBN tiles, 256 thr (2x2 waves),
// chunk-XOR swizzle (0 conflicts), dbuf + prefetch + counted vmcnt.
// MINW: min waves/EU for launch_bounds (2 for MI=8 variants: acc 128 VGPR).
// MODE 0: f32 C = acc+bias ; 1: f32 C += acc+bias ; 2: bf16 C = acc+bias ;
// MODE 3: silu-fused (pair-interleaved Bt): bf16 gate out [M][2816]
// MODE 4: f32 C = acc + dual-bias (cols 0..287 bias, 384..767 bias2)
template <int MODE, int BM, int BN, int MINW = 4>
__global__ __launch_bounds__(256, MINW) void k_gemm(
    const u16* __restrict__ A, const u16* __restrict__ Bt,
    const float* __restrict__ bias, const float* __restrict__ bias2,
    void* __restrict__ C, int N, int K) {
  constexpr int MI = BM / 32, NJ = BN / 32;
  constexpr int AL = BM / 64, BL = BN / 64;    // gll16 per stage (64-row groups)
  __shared__ u16 lA[2][BM * 32];
  __shared__ u16 lB[2][BN * 32];
  const int tid = threadIdx.x;
  const int gx = gridDim.x;
  const int nwg = gx * gridDim.y;
  const int f = blockIdx.y * gx + blockIdx.x;
  const int f2 = (f & 7) * (nwg >> 3) + (f >> 3);   // xcd swizzle, nwg%8==0
  const int bx = f2 % gx, by = f2 / gx;
  const long m0 = (long)bx * BM, n0 = (long)by * BN;
  const int lane = tid & 63, wid = tid >> 6;
  const int wm = (wid >> 1) * (BM / 2), wn = (wid & 1) * (BN / 2);
  const int fr = lane & 15, l4 = lane >> 4;
  const int sw = (fr >> 1) & 3;

  const int rs = tid >> 2;                            // stage row (per 64-group)
  const int cs = ((tid & 3) ^ ((rs >> 1) & 3)) * 8;   // swizzled chunk (involution)
  const u16* a0 = A + (m0 + rs) * (long)K + cs;
  const u16* b0 = Bt + (n0 + rs) * (long)K + cs;
  const long g64 = 64L * K;

  f32x4 acc[MI][NJ] = {};
  const int NT = K >> 5;

  // each 64-row group = 64 rows x 32 u16 = 2048 LDS elements
  auto stage = [&](int buf, int kk) {
    #pragma unroll
    for (int g = 0; g < AL; ++g)
      gll16(a0 + g * g64 + kk, (u16*)lA[buf] + g * 2048 + tid * 8);
    #pragma unroll
    for (int g = 0; g < BL; ++g)
      gll16(b0 + g * g64 + kk, (u16*)lB[buf] + g * 2048 + tid * 8);
  };

  stage(0, 0);

  for (int j = 0; j < NT; ++j) {
    const int cur = j & 1;
    const int kk1 = (j + 1) << 5;
    if (j + 1 < NT) {
      stage(cur ^ 1, kk1);
      if constexpr (AL + BL == 2) VMW(2);
      else if constexpr (AL + BL == 3) VMW(3);
      else if constexpr (AL + BL == 4) VMW(4);
      else if constexpr (AL + BL == 5) VMW(5);
      else VMW(6);
    } else {
      VMW(0);
    }
    __builtin_amdgcn_s_barrier();
    FENCE;
    bf16x8 af[MI], bfr[NJ];
    #pragma unroll
    for (int i = 0; i < MI; i++)
      af[i] = *(const bf16x8*)&lA[cur][(wm + i * 16 + fr) * 32 + ((l4 ^ sw) * 8)];
    #pragma unroll
    for (int jj = 0; jj < NJ; jj++)
      bfr[jj] = *(const bf16x8*)&lB[cur][(wn + jj * 16 + fr) * 32 + ((l4 ^ sw) * 8)];
    #pragma unroll
    for (int i = 0; i < MI; i++)
      #pragma unroll
      for (int jj = 0; jj < NJ; jj++)
        acc[i][jj] = __builtin_amdgcn_mfma_f32_16x16x32_bf16(af[i], bfr[jj], acc[i][jj], 0, 0, 0);
    FENCE;
    __builtin_amdgcn_s_barrier();
    FENCE;
  }

  const long r0 = m0 + wm + l4 * 4;
  const long c0 = n0 + wn + fr;
  if (MODE == 3) {
    u16* G = (u16*)C;
    #pragma unroll
    for (int j = 0; j < NJ; ++j) {
      long col = c0 + j * 16;
      int pcol = (int)((col & 1) ? (col >> 1) + 2816 : (col >> 1));
      float bs = bias[pcol];
      #pragma unroll
      for (int i = 0; i < MI; ++i)
        #pragma unroll
        for (int r = 0; r < 4; ++r) {
          float val = acc[i][j][r] + bs;
          float oth = __shfl_xor(val, 1);
          if (!(col & 1)) {
            float x = oth;
            float gv = val * x * (1.f / (1.f + __expf(-x)));
            G[(r0 + i * 16 + r) * 2816L + (col >> 1)] = f2b(gv);
          }
        }
    }
  } else {
    #pragma unroll
    for (int j = 0; j < NJ; ++j) {
      long col = c0 + j * 16;
      float bs;
      if (MODE == 4)
        bs = (col < 288) ? bias[col] : ((col >= 384) ? bias2[col - 384] : 0.f);
      else
        bs = bias[col];
      #pragma unroll
      for (int i = 0; i < MI; ++i)
        #pragma unroll
        for (int r = 0; r < 4; ++r) {
          long row = r0 + i * 16 + r;
          float val = acc[i][j][r] + bs;
          if (MODE == 0 || MODE == 4) ((float*)C)[row * N + col] = val;
          else if (MODE == 1) { float* p = (float*)C + row * N + col; *p += val; }
          else ((u16*)C)[row * N + col] = f2b(val);
        }
    }
  }
}

extern "C" void kernel_launch(void* const* d_in, const int* in_sizes, int n_in,
                              void* d_out, int out_size, void* d_ws, size_t ws_size,
                              hipStream_t stream) {
  (void)in_sizes; (void)n_in; (void)out_size; (void)ws_size;
  const int*   tokens    = (const int*)  d_in[0];
  const float* embed     = (const float*)d_in[1];
  const float* w_kv_down = (const float*)d_in[2];
  const float* b_kv_down = (const float*)d_in[3];
  const float* w_q_down  = (const float*)d_in[4];
  const float* b_q_down  = (const float*)d_in[5];
  const float* w_kv_up   = (const float*)d_in[6];
  const float* b_kv_up   = (const float*)d_in[7];
  const float* w_q_up    = (const float*)d_in[8];
  const float* b_q_up    = (const float*)d_in[9];
  const float* w_o       = (const float*)d_in[10];
  const float* b_o       = (const float*)d_in[11];
  const float* kv_norm_w = (const float*)d_in[12];
  const float* q_norm_w  = (const float*)d_in[13];
  const float* norm1_w   = (const float*)d_in[14];
  const float* norm2_w   = (const float*)d_in[15];
  const float* w_in      = (const float*)d_in[16];
  const float* b_in      = (const float*)d_in[17];
  const float* w_out     = (const float*)d_in[18];
  const float* b_out     = (const float*)d_in[19];
  const float* norm_f_w  = (const float*)d_in[20];
  const float* w_head    = (const float*)d_in[21];
  const float* b_head    = (const float*)d_in[22];

  char* base = (char*)d_ws;
  size_t off = 0;
  auto alloc = [&](size_t bytes) -> void* {
    void* p = base + off;
    off += (bytes + 255) & ~(size_t)255;
    return p;
  };
  u16* warena = (u16*)alloc((size_t)32000 * 1024 * 2);
  u16* wT_dq    = warena;                        // 768 x 1024
  u16* wT_kvup  = wT_dq   + 768 * 1024;          // 2048 x 256
  u16* wT_qup   = wT_kvup + 2048 * 256;          // 1536 x 384
  u16* wT_o     = wT_qup  + 1536 * 384;          // 1024 x 1024
  u16* wT_in    = wT_o    + 1024 * 1024;         // 5632 x 1024 (pair-interleaved)
  u16* wT_out   = wT_in   + 5632 * 1024;         // 1024 x 2816

  float* h     = (float*)alloc((size_t)Mm * 1024 * 4);
  u16*   xn    = (u16*)  alloc((size_t)Mm * 1024 * 2);
  float* ckvq  = (float*)alloc((size_t)Mm * 768 * 4);
  u16*   ckvn  = (u16*)  alloc((size_t)Mm * 256 * 2);
  u16*   kv    = (u16*)  alloc((size_t)Mm * 2048 * 2);
  u16*   qdn   = (u16*)  alloc((size_t)Mm * 384 * 2);
  u16*   qf    = (u16*)  alloc((size_t)Mm * 1536 * 2);   // bf16 now
  u16*   Qb    = (u16*)  alloc((size_t)32 * 1024 * QKD * 2);
  u16*   Kb    = (u16*)  alloc((size_t)32 * 1024 * QKD * 2);
  u16*   Vt    = (u16*)  alloc((size_t)32 * 64 * 1024 * 2);
  u16*   attn  = (u16*)  alloc((size_t)Mm * 1024 * 2);
  u16*   gate  = (u16*)  alloc((size_t)Mm * 2816 * 2);

  dim3 tb(32, 8);

  k_embed<<<Mm, 256, 0, stream>>>(tokens, embed, h);

  for (int l = 0; l < 4; l++) {
    WJobs jb;
    jb.j[0] = { w_kv_down + (size_t)l * 1024 * 288,  wT_dq,              1024, 288,  0, 96 };
    jb.j[1] = { w_q_down  + (size_t)l * 1024 * 384,  wT_dq + 384 * 1024, 1024, 384,  0, 96 };
    jb.j[2] = { w_kv_up   + (size_t)l * 256 * 2048,  wT_kvup,            256,  2048, 0, 128 };
    jb.j[3] = { w_q_up    + (size_t)l * 384 * 1536,  wT_qup,             384,  1536, 0, 144 };
    jb.j[4] = { w_o       + (size_t)l * 1024 * 1024, wT_o,               1024, 1024, 0, 256 };
    jb.j[5] = { w_in      + (size_t)l * 1024 * 5632, wT_in,              1024, 5632, 1, 1408 };
    jb.j[6] = { w_out     + (size_t)l * 2816 * 1024, wT_out,             2816, 1024, 0, 704 };
    k_wcvt_batch<<<2832, 256, 0, stream>>>(jb, 7);

    k_rms<<<Mm, 256, 0, stream>>>(h, 1024, norm1_w + l * 1024, xn, 1024);
    // fused kv_down+q_down with dual bias (MODE 4): 64x64 tiles, grid 32x12
    k_gemm<4, 64, 64><<<dim3(32, 12), 256, 0, stream>>>(xn, wT_dq, b_kv_down + l * 288,
                                                        b_q_down + l * 384, ckvq, 768, 1024);
    k_rms<<<Mm, 256, 0, stream>>>(ckvq, 768, kv_norm_w + l * 256, ckvn, 256);
    // kv_up -> bf16, 64x128 tiles, grid 32x16
    k_gemm<2, 64, 128><<<dim3(32, 16), 256, 0, stream>>>(ckvn, wT_kvup, b_kv_up + l * 2048,
                                                         nullptr, kv, 2048, 256);
    k_rms<<<Mm, 256, 0, stream>>>(ckvq + 384, 768, q_norm_w + l * 384, qdn, 384);
    // q_up -> bf16 (MODE 2): 64x64, grid 32x24
    k_gemm<2, 64, 64><<<dim3(32, 24), 256, 0, stream>>>(qdn, wT_qup, b_q_up + l * 1536,
                                                        nullptr, qf, 1536, 384);
    k_buildqk<<<dim3(Ss, 32), 128, 0, stream>>>(qf, kv, ckvq, Qb, Kb);
    k_buildvt<<<dim3(32, 32, 2), tb, 0, stream>>>(kv, Vt);
    k_flash<<<dim3(16, 32), 256, 0, stream>>>(Qb, Kb, Vt, attn);
    // w_o residual: 64x64, grid 32x16
    k_gemm<1, 64, 64><<<dim3(32, 16), 256, 0, stream>>>(attn, wT_o, b_o + l * 1024,
                                                        nullptr, h, 1024, 1024);
    k_rms<<<Mm, 256, 0, stream>>>(h, 1024, norm2_w + l * 1024, xn, 1024);
    // w_in + silu: 256x128 (MI=8 LDS-traffic-lean), grid 8x44
    k_gemm<3, 256, 128, 2><<<dim3(8, 44), 256, 0, stream>>>(xn, wT_in, b_in + l * 5632,
                                                            nullptr, gate, 5632, 1024);
    // w_out residual: 64x64, grid 32x16
    k_gemm<1, 64, 64><<<dim3(32, 16), 256, 0, stream>>>(gate, wT_out, b_out + l * 1024,
                                                        nullptr, h, 1024, 2816);
  }

  k_rms<<<Mm, 256, 0, stream>>>(h, 1024, norm_f_w, xn, 1024);
  {
    WJobs jbh;
    jbh.j[0] = { w_head, warena, 1024, 32000, 0, 8000 };
    k_wcvt_batch<<<8000, 256, 0, stream>>>(jbh, 1);
  }
  // head: 256x128 tiles (MI=8), grid 8x250 = 2000 blocks, 2 blocks/CU
  k_gemm<0, 256, 128, 2><<<dim3(8, 250), 256, 0, stream>>>(xn, warena, b_head,
                                                           nullptr, (float*)d_out, 32000, 1024);
}

// Round 14
// 1048.247 us; speedup vs baseline: 1.0704x; 1.0704x over previous
//
#include <hip/hip_runtime.h>
#include <cstdint>
#include <cstddef>

typedef unsigned short u16;
typedef __attribute__((__ext_vector_type__(8))) __bf16 bf16x8;
typedef __attribute__((__ext_vector_type__(4))) float f32x4;
typedef __attribute__((__ext_vector_type__(8))) unsigned short u16x8;

#define DEVI __device__ __forceinline__

constexpr int Bb = 2, Ss = 1024, Dd = 1024, Hh = 16;
constexpr int Mm = Bb * Ss;
constexpr int QKD = 128;
constexpr float EPSF = 1.1920929e-07f;
constexpr float NEG = -1e30f;
constexpr float QSCALE = 0.10206207261596577f; // 1/sqrt(96)
constexpr float LOG1E4_16 = 9.210340371976184f / 16.f;

DEVI u16 f2b(float f) {
  union { float f; uint32_t u; } a; a.f = f;
  uint32_t r = a.u + 0x7FFFu + ((a.u >> 16) & 1u);
  return (u16)(r >> 16);
}
DEVI float b2f(u16 h) {
  union { uint32_t u; float f; } a; a.u = ((uint32_t)h) << 16; return a.f;
}

// ---------------- batched fp32 -> bf16 transposed weight conversion
struct WJob { const float* src; u16* dst; int K; int N; int perm; int ntiles; };
struct WJobs { WJob j[7]; };

__global__ __launch_bounds__(256) void k_wcvt_batch(WJobs jobs, int njobs) {
  int t = blockIdx.x;
  int ji = 0;
  while (ji < njobs - 1 && t >= jobs.j[ji].ntiles) { t -= jobs.j[ji].ntiles; ++ji; }
  const float* __restrict__ src = jobs.j[ji].src;
  u16* __restrict__ dst = jobs.j[ji].dst;
  const int K = jobs.j[ji].K, N = jobs.j[ji].N, perm = jobs.j[ji].perm;
  const int ktiles = K >> 6;
  const int bk = (t % ktiles) * 64;
  const int bn = (t / ktiles) * 64;
  __shared__ float ts[64][65];
  const int tid = threadIdx.x;
  {
    int c4 = tid & 15, r = tid >> 4;
    #pragma unroll
    for (int p = 0; p < 4; ++p) {
      int row = r + p * 16;
      int col = bn + c4 * 4;
      float4 v = make_float4(0.f, 0.f, 0.f, 0.f);
      if (col < N) v = *(const float4*)(src + (size_t)(bk + row) * N + col);
      ts[row][c4 * 4 + 0] = v.x; ts[row][c4 * 4 + 1] = v.y;
      ts[row][c4 * 4 + 2] = v.z; ts[row][c4 * 4 + 3] = v.w;
    }
  }
  __syncthreads();
  {
    int k8 = tid & 7, c = tid >> 3;
    #pragma unroll
    for (int p = 0; p < 2; ++p) {
      int cc = c + p * 32;
      int gcol = bn + cc;
      int row = perm ? ((gcol < 2816) ? (gcol * 2) : ((gcol - 2816) * 2 + 1)) : gcol;
      u16x8 o;
      #pragma unroll
      for (int q = 0; q < 8; ++q) o[q] = f2b(ts[k8 * 8 + q][cc]);
      *(u16x8*)(dst + (size_t)row * K + bk + k8 * 8) = o;
    }
  }
}

// ---------------- embedding gather
__global__ void k_embed(const int* __restrict__ tok, const float* __restrict__ emb,
                        float* __restrict__ h) {
  int m = blockIdx.x;
  int t = tok[m];
  const float4* src = (const float4*)(emb + (size_t)t * Dd);
  float4* dst = (float4*)(h + (size_t)m * Dd);
  dst[threadIdx.x] = src[threadIdx.x];
}

// ---------------- rmsnorm: f32 (stride inStride) -> bf16 (stride K)
__global__ void k_rms(const float* __restrict__ in, int inStride,
                      const float* __restrict__ w, u16* __restrict__ out, int K) {
  int m = blockIdx.x;
  const float* x = in + (size_t)m * inStride;
  float ss = 0.f;
  for (int i = threadIdx.x; i < K; i += 256) { float v = x[i]; ss += v * v; }
  #pragma unroll
  for (int off = 32; off; off >>= 1) ss += __shfl_xor(ss, off);
  __shared__ float red[4];
  if ((threadIdx.x & 63) == 0) red[threadIdx.x >> 6] = ss;
  __syncthreads();
  float r = rsqrtf((red[0] + red[1] + red[2] + red[3]) / (float)K + EPSF);
  for (int i = threadIdx.x; i < K; i += 256)
    out[(size_t)m * K + i] = f2b(x[i] * r * w[i]);
}

// ---------------- build Q and K (rope cols 64..95; Q scaled; pad to 128)
__global__ void k_buildqk(const u16* __restrict__ qf, const u16* __restrict__ kv,
                          const float* __restrict__ ckvq, u16* __restrict__ Q,
                          u16* __restrict__ Kb) {
  int s = blockIdx.x, bh = blockIdx.y;
  int b = bh >> 4, h = bh & 15;
  int d = threadIdx.x;
  int m = b * Ss + s;
  int j = d - 64;
  float sn = 0.f, cs = 0.f;
  if (d >= 64 && d < 96) {
    float theta = __expf(-(float)(j & 15) * LOG1E4_16);
    __sincosf((float)s * theta, &sn, &cs);
  }
  const u16* qrow = qf + (size_t)m * (Hh * 96) + h * 96;
  float qv = 0.f;
  if (d < 64) qv = b2f(qrow[d]);
  else if (d < 96) {
    float x = b2f(qrow[64 + j]), o = b2f(qrow[64 + (j ^ 16)]);
    qv = x * cs + ((j < 16) ? -o : o) * sn;
  }
  Q[((size_t)bh * Ss + s) * QKD + d] = f2b(qv * QSCALE);
  u16 kvv = 0;
  if (d < 64) kvv = kv[(size_t)m * 2048 + h * 128 + d];
  else if (d < 96) {
    const float* rr = ckvq + (size_t)m * 768 + 256;
    float x = rr[j], o = rr[j ^ 16];
    kvv = f2b(x * cs + ((j < 16) ? -o : o) * sn);
  }
  Kb[((size_t)bh * Ss + s) * QKD + d] = kvv;
}

// ---------------- build V^T (per head: [64][1024]), bf16 in -> bf16 out
__global__ void k_buildvt(const u16* __restrict__ kv, u16* __restrict__ Vt) {
  __shared__ u16 t[32][33];
  int bh = blockIdx.x, s0 = blockIdx.y * 32, d0 = blockIdx.z * 32;
  int b = bh >> 4, h = bh & 15;
  int tx = threadIdx.x, ty = threadIdx.y;
  #pragma unroll
  for (int i = ty; i < 32; i += 8) {
    int s = s0 + i, d = d0 + tx;
    t[i][tx] = kv[(size_t)(b * Ss + s) * 2048 + h * 128 + 64 + d];
  }
  __syncthreads();
  #pragma unroll
  for (int i = ty; i < 32; i += 8) {
    int d = d0 + i, s = s0 + tx;
    Vt[((size_t)bh * 64 + d) * Ss + s] = t[tx][i];
  }
}

#define GAS __attribute__((address_space(1)))
#define LAS __attribute__((address_space(3)))
DEVI void gll16(const void* g, void* l) {
  __builtin_amdgcn_global_load_lds((GAS const void*)g, (LAS void*)l, 16, 0, 0);
}
#define VMW(n) asm volatile("s_waitcnt vmcnt(" #n ")" ::: "memory")
#define FENCE asm volatile("" ::: "memory")

// ---------------- fused flash attention (causal), bf16 in/out
// grid (8 pairs, 32 bh), 256 thr. Block handles q-tiles {p, 15-p}: 17 K-steps,
// perfectly load-balanced. Double-buffered K/V with counted vmcnt.
__global__ __launch_bounds__(256) void k_flash(
    const u16* __restrict__ Qg, const u16* __restrict__ Kg,
    const u16* __restrict__ Vtg, u16* __restrict__ attn) {
  __shared__ u16 lK[2][64 * 128];
  __shared__ u16 lV[2][64 * 64];
  __shared__ u16 lP[4][16 * 64];
  const int tid = threadIdx.x;
  const int pair = blockIdx.x, bh = blockIdx.y;
  const int b = bh >> 4, h = bh & 15;
  const int lane = tid & 63, w = tid >> 6;
  const int g = lane >> 4, fr = lane & 15;
  const u16* Qh = Qg + (size_t)bh * Ss * QKD;
  const u16* Kh = Kg + (size_t)bh * Ss * QKD;
  const u16* Vh = Vtg + (size_t)bh * 64 * Ss;

  auto stageKV = [&](int buf, int kt) {
    int r = tid >> 4, c = tid & 15;
    #pragma unroll
    for (int gg = 0; gg < 4; ++gg) {
      int row = gg * 16 + r;
      const u16* src = Kh + (size_t)(kt * 64 + row) * QKD + ((c ^ (row & 7)) * 8);
      gll16(src, (u16*)lK[buf] + gg * 2048 + tid * 8);
    }
    int r2 = tid >> 3, c2 = tid & 7;
    #pragma unroll
    for (int gg = 0; gg < 2; ++gg) {
      int d = gg * 32 + r2;
      const u16* src = Vh + (size_t)d * Ss + kt * 64 + ((c2 ^ (d & 7)) * 8);
      gll16(src, (u16*)lV[buf] + gg * 2048 + tid * 8);
    }
  };

  for (int pass = 0; pass < 2; ++pass) {
    const int qt = pass ? (15 - pair) : pair;
    const int q0 = qt * 64;
    bf16x8 af[4];
    const u16* qrow = Qh + (size_t)(q0 + w * 16 + fr) * QKD + g * 8;
    #pragma unroll
    for (int k4 = 0; k4 < 4; ++k4) af[k4] = *(const bf16x8*)(qrow + k4 * 32);

    f32x4 acc_o[4] = {};
    float mrow = NEG, lrow = 0.f;

    stageKV(0, 0);

    for (int kt = 0; kt <= qt; ++kt) {
      const int cur = kt & 1;
      if (kt < qt) { stageKV(cur ^ 1, kt + 1); VMW(6); }
      else { VMW(0); }
      __builtin_amdgcn_s_barrier();
      FENCE;

      f32x4 accs[4] = {};
      #pragma unroll
      for (int j = 0; j < 4; ++j) {
        #pragma unroll
        for (int k4 = 0; k4 < 4; ++k4) {
          int row = j * 16 + fr;
          int ch = (k4 * 4 + g) ^ (row & 7);
          bf16x8 kf = *(const bf16x8*)&lK[cur][row * 128 + ch * 8];
          accs[j] = __builtin_amdgcn_mfma_f32_16x16x32_bf16(kf, af[k4], accs[j], 0, 0, 0);
        }
      }

      float p[16];
      float tmax = NEG;
      #pragma unroll
      for (int j = 0; j < 4; ++j)
        #pragma unroll
        for (int r = 0; r < 4; ++r) {
          float s = accs[j][r];
          int kloc = j * 16 + 4 * g + r;
          bool valid = (kt < qt) || (kloc <= w * 16 + fr);
          s = valid ? s : NEG;
          p[j * 4 + r] = s;
          tmax = fmaxf(tmax, s);
        }
      tmax = fmaxf(tmax, __shfl_xor(tmax, 16));
      tmax = fmaxf(tmax, __shfl_xor(tmax, 32));
      float mnew = fmaxf(mrow, tmax);
      float scale = __expf(mrow - mnew);
      float tsum = 0.f;
      #pragma unroll
      for (int i = 0; i < 16; ++i) { p[i] = __expf(p[i] - mnew); tsum += p[i]; }
      tsum += __shfl_xor(tsum, 16);
      tsum += __shfl_xor(tsum, 32);
      lrow = lrow * scale + tsum;
      mrow = mnew;

      #pragma unroll
      for (int j = 0; j < 4; ++j)
        #pragma unroll
        for (int t = 0; t < 2; ++t) {
          uint32_t u = (uint32_t)f2b(p[j * 4 + 2 * t]) |
                       ((uint32_t)f2b(p[j * 4 + 2 * t + 1]) << 16);
          int kp = 8 * j + 2 * g + t;
          int ch = kp >> 2, wi = kp & 3;
          ((uint32_t*)lP[w])[fr * 32 + ((ch ^ (fr & 7)) << 2) + wi] = u;
        }

      float sc_q[4];
      #pragma unroll
      for (int r = 0; r < 4; ++r) sc_q[r] = __shfl(scale, 4 * g + r);
      #pragma unroll
      for (int j2 = 0; j2 < 4; ++j2)
        #pragma unroll
        for (int r = 0; r < 4; ++r) acc_o[j2][r] *= sc_q[r];

      #pragma unroll
      for (int ksub = 0; ksub < 2; ++ksub) {
        int chp = (4 * ksub + g) ^ (fr & 7);
        bf16x8 pa = *(const bf16x8*)&((const u16*)lP[w])[fr * 64 + chp * 8];
        #pragma unroll
        for (int j2 = 0; j2 < 4; ++j2) {
          int d = j2 * 16 + fr;
          int chv = (ksub * 4 + g) ^ (d & 7);
          bf16x8 vf = *(const bf16x8*)&lV[cur][d * 64 + chv * 8];
          acc_o[j2] = __builtin_amdgcn_mfma_f32_16x16x32_bf16(pa, vf, acc_o[j2], 0, 0, 0);
        }
      }
      FENCE;
      __builtin_amdgcn_s_barrier();
      FENCE;
    }

    float li[4];
    #pragma unroll
    for (int r = 0; r < 4; ++r) li[r] = 1.f / __shfl(lrow, 4 * g + r);
    #pragma unroll
    for (int j2 = 0; j2 < 4; ++j2)
      #pragma unroll
      for (int r = 0; r < 4; ++r) {
        int q = q0 + w * 16 + 4 * g + r;
        int d = j2 * 16 + fr;
        attn[((size_t)(b * Ss) + q) * Dd + h * 64 + d] = f2b(acc_o[j2][r] * li[r]);
      }
  }
}

// ---------------- generic bf16 MFMA GEMM, BMxBN tiles, 256 thr (2x2 waves),
// chunk-XOR swizzle (0 conflicts), dbuf + prefetch + counted vmcnt.
// MODE 0: f32 C = acc+bias ; 1: f32 C += acc+bias ; 2: bf16 C = acc+bias ;
// MODE 3: silu-fused (pair-interleaved Bt): bf16 gate out [M][2816]
// MODE 4: f32 C = acc + dual-bias (cols 0..287 bias, 384..767 bias2)
template <int MODE, int BM, int BN, int MINW = 4>
__global__ __launch_bounds__(256, MINW) void k_gemm(
    const u16* __restrict__ A, const u16* __restrict__ Bt,
    const float* __restrict__ bias, const float* __restrict__ bias2,
    void* __restrict__ C, int N, int K) {
  constexpr int MI = BM / 32, NJ = BN / 32;
  constexpr int AL = BM / 64, BL = BN / 64;    // gll16 per stage (64-row groups)
  __shared__ u16 lA[2][BM * 32];
  __shared__ u16 lB[2][BN * 32];
  const int tid = threadIdx.x;
  const int gx = gridDim.x;
  const int nwg = gx * gridDim.y;
  const int f = blockIdx.y * gx + blockIdx.x;
  const int f2 = (f & 7) * (nwg >> 3) + (f >> 3);   // xcd swizzle, nwg%8==0
  const int bx = f2 % gx, by = f2 / gx;
  const long m0 = (long)bx * BM, n0 = (long)by * BN;
  const int lane = tid & 63, wid = tid >> 6;
  const int wm = (wid >> 1) * (BM / 2), wn = (wid & 1) * (BN / 2);
  const int fr = lane & 15, l4 = lane >> 4;
  const int sw = (fr >> 1) & 3;

  const int rs = tid >> 2;                            // stage row (per 64-group)
  const int cs = ((tid & 3) ^ ((rs >> 1) & 3)) * 8;   // swizzled chunk (involution)
  const u16* a0 = A + (m0 + rs) * (long)K + cs;
  const u16* b0 = Bt + (n0 + rs) * (long)K + cs;
  const long g64 = 64L * K;

  f32x4 acc[MI][NJ] = {};
  const int NT = K >> 5;

  // each 64-row group = 64 rows x 32 u16 = 2048 LDS elements
  auto stage = [&](int buf, int kk) {
    #pragma unroll
    for (int g = 0; g < AL; ++g)
      gll16(a0 + g * g64 + kk, (u16*)lA[buf] + g * 2048 + tid * 8);
    #pragma unroll
    for (int g = 0; g < BL; ++g)
      gll16(b0 + g * g64 + kk, (u16*)lB[buf] + g * 2048 + tid * 8);
  };

  stage(0, 0);

  for (int j = 0; j < NT; ++j) {
    const int cur = j & 1;
    const int kk1 = (j + 1) << 5;
    if (j + 1 < NT) {
      stage(cur ^ 1, kk1);
      if constexpr (AL + BL == 2) VMW(2);
      else if constexpr (AL + BL == 3) VMW(3);
      else if constexpr (AL + BL == 4) VMW(4);
      else if constexpr (AL + BL == 5) VMW(5);
      else VMW(6);
    } else {
      VMW(0);
    }
    __builtin_amdgcn_s_barrier();
    FENCE;
    bf16x8 af[MI], bfr[NJ];
    #pragma unroll
    for (int i = 0; i < MI; i++)
      af[i] = *(const bf16x8*)&lA[cur][(wm + i * 16 + fr) * 32 + ((l4 ^ sw) * 8)];
    #pragma unroll
    for (int jj = 0; jj < NJ; jj++)
      bfr[jj] = *(const bf16x8*)&lB[cur][(wn + jj * 16 + fr) * 32 + ((l4 ^ sw) * 8)];
    #pragma unroll
    for (int i = 0; i < MI; i++)
      #pragma unroll
      for (int jj = 0; jj < NJ; jj++)
        acc[i][jj] = __builtin_amdgcn_mfma_f32_16x16x32_bf16(af[i], bfr[jj], acc[i][jj], 0, 0, 0);
    FENCE;
    __builtin_amdgcn_s_barrier();
    FENCE;
  }

  const long r0 = m0 + wm + l4 * 4;
  const long c0 = n0 + wn + fr;
  if (MODE == 3) {
    u16* G = (u16*)C;
    #pragma unroll
    for (int j = 0; j < NJ; ++j) {
      long col = c0 + j * 16;
      int pcol = (int)((col & 1) ? (col >> 1) + 2816 : (col >> 1));
      float bs = bias[pcol];
      #pragma unroll
      for (int i = 0; i < MI; ++i)
        #pragma unroll
        for (int r = 0; r < 4; ++r) {
          float val = acc[i][j][r] + bs;
          float oth = __shfl_xor(val, 1);
          if (!(col & 1)) {
            float x = oth;
            float gv = val * x * (1.f / (1.f + __expf(-x)));
            G[(r0 + i * 16 + r) * 2816L + (col >> 1)] = f2b(gv);
          }
        }
    }
  } else {
    #pragma unroll
    for (int j = 0; j < NJ; ++j) {
      long col = c0 + j * 16;
      float bs;
      if (MODE == 4)
        bs = (col < 288) ? bias[col] : ((col >= 384) ? bias2[col - 384] : 0.f);
      else
        bs = bias[col];
      #pragma unroll
      for (int i = 0; i < MI; ++i)
        #pragma unroll
        for (int r = 0; r < 4; ++r) {
          long row = r0 + i * 16 + r;
          float val = acc[i][j][r] + bs;
          if (MODE == 0 || MODE == 4) ((float*)C)[row * N + col] = val;
          else if (MODE == 1) { float* p = (float*)C + row * N + col; *p += val; }
          else ((u16*)C)[row * N + col] = f2b(val);
        }
    }
  }
}

extern "C" void kernel_launch(void* const* d_in, const int* in_sizes, int n_in,
                              void* d_out, int out_size, void* d_ws, size_t ws_size,
                              hipStream_t stream) {
  (void)in_sizes; (void)n_in; (void)out_size; (void)ws_size;
  const int*   tokens    = (const int*)  d_in[0];
  const float* embed     = (const float*)d_in[1];
  const float* w_kv_down = (const float*)d_in[2];
  const float* b_kv_down = (const float*)d_in[3];
  const float* w_q_down  = (const float*)d_in[4];
  const float* b_q_down  = (const float*)d_in[5];
  const float* w_kv_up   = (const float*)d_in[6];
  const float* b_kv_up   = (const float*)d_in[7];
  const float* w_q_up    = (const float*)d_in[8];
  const float* b_q_up    = (const float*)d_in[9];
  const float* w_o       = (const float*)d_in[10];
  const float* b_o       = (const float*)d_in[11];
  const float* kv_norm_w = (const float*)d_in[12];
  const float* q_norm_w  = (const float*)d_in[13];
  const float* norm1_w   = (const float*)d_in[14];
  const float* norm2_w   = (const float*)d_in[15];
  const float* w_in      = (const float*)d_in[16];
  const float* b_in      = (const float*)d_in[17];
  const float* w_out     = (const float*)d_in[18];
  const float* b_out     = (const float*)d_in[19];
  const float* norm_f_w  = (const float*)d_in[20];
  const float* w_head    = (const float*)d_in[21];
  const float* b_head    = (const float*)d_in[22];

  char* base = (char*)d_ws;
  size_t off = 0;
  auto alloc = [&](size_t bytes) -> void* {
    void* p = base + off;
    off += (bytes + 255) & ~(size_t)255;
    return p;
  };
  u16* warena = (u16*)alloc((size_t)32000 * 1024 * 2);
  u16* wT_dq    = warena;                        // 768 x 1024
  u16* wT_kvup  = wT_dq   + 768 * 1024;          // 2048 x 256
  u16* wT_qup   = wT_kvup + 2048 * 256;          // 1536 x 384
  u16* wT_o     = wT_qup  + 1536 * 384;          // 1024 x 1024
  u16* wT_in    = wT_o    + 1024 * 1024;         // 5632 x 1024 (pair-interleaved)
  u16* wT_out   = wT_in   + 5632 * 1024;         // 1024 x 2816

  float* h     = (float*)alloc((size_t)Mm * 1024 * 4);
  u16*   xn    = (u16*)  alloc((size_t)Mm * 1024 * 2);
  float* ckvq  = (float*)alloc((size_t)Mm * 768 * 4);
  u16*   ckvn  = (u16*)  alloc((size_t)Mm * 256 * 2);
  u16*   kv    = (u16*)  alloc((size_t)Mm * 2048 * 2);
  u16*   qdn   = (u16*)  alloc((size_t)Mm * 384 * 2);
  u16*   qf    = (u16*)  alloc((size_t)Mm * 1536 * 2);
  u16*   Qb    = (u16*)  alloc((size_t)32 * 1024 * QKD * 2);
  u16*   Kb    = (u16*)  alloc((size_t)32 * 1024 * QKD * 2);
  u16*   Vt    = (u16*)  alloc((size_t)32 * 64 * 1024 * 2);
  u16*   attn  = (u16*)  alloc((size_t)Mm * 1024 * 2);
  u16*   gate  = (u16*)  alloc((size_t)Mm * 2816 * 2);

  dim3 tb(32, 8);

  k_embed<<<Mm, 256, 0, stream>>>(tokens, embed, h);

  for (int l = 0; l < 4; l++) {
    WJobs jb;
    jb.j[0] = { w_kv_down + (size_t)l * 1024 * 288,  wT_dq,              1024, 288,  0, 96 };
    jb.j[1] = { w_q_down  + (size_t)l * 1024 * 384,  wT_dq + 384 * 1024, 1024, 384,  0, 96 };
    jb.j[2] = { w_kv_up   + (size_t)l * 256 * 2048,  wT_kvup,            256,  2048, 0, 128 };
    jb.j[3] = { w_q_up    + (size_t)l * 384 * 1536,  wT_qup,             384,  1536, 0, 144 };
    jb.j[4] = { w_o       + (size_t)l * 1024 * 1024, wT_o,               1024, 1024, 0, 256 };
    jb.j[5] = { w_in      + (size_t)l * 1024 * 5632, wT_in,              1024, 5632, 1, 1408 };
    jb.j[6] = { w_out     + (size_t)l * 2816 * 1024, wT_out,             2816, 1024, 0, 704 };
    k_wcvt_batch<<<2832, 256, 0, stream>>>(jb, 7);

    k_rms<<<Mm, 256, 0, stream>>>(h, 1024, norm1_w + l * 1024, xn, 1024);
    // fused kv_down+q_down with dual bias (MODE 4): 64x64 tiles, grid 32x12
    k_gemm<4, 64, 64><<<dim3(32, 12), 256, 0, stream>>>(xn, wT_dq, b_kv_down + l * 288,
                                                        b_q_down + l * 384, ckvq, 768, 1024);
    k_rms<<<Mm, 256, 0, stream>>>(ckvq, 768, kv_norm_w + l * 256, ckvn, 256);
    // kv_up -> bf16, 64x128 tiles, grid 32x16
    k_gemm<2, 64, 128><<<dim3(32, 16), 256, 0, stream>>>(ckvn, wT_kvup, b_kv_up + l * 2048,
                                                         nullptr, kv, 2048, 256);
    k_rms<<<Mm, 256, 0, stream>>>(ckvq + 384, 768, q_norm_w + l * 384, qdn, 384);
    // q_up -> bf16 (MODE 2): 64x64, grid 32x24
    k_gemm<2, 64, 64><<<dim3(32, 24), 256, 0, stream>>>(qdn, wT_qup, b_q_up + l * 1536,
                                                        nullptr, qf, 1536, 384);
    k_buildqk<<<dim3(Ss, 32), 128, 0, stream>>>(qf, kv, ckvq, Qb, Kb);
    k_buildvt<<<dim3(32, 32, 2), tb, 0, stream>>>(kv, Vt);
    // flash: pair-balanced (17 K-steps per block), grid 8x32
    k_flash<<<dim3(8, 32), 256, 0, stream>>>(Qb, Kb, Vt, attn);
    // w_o residual: 64x64, grid 32x16
    k_gemm<1, 64, 64><<<dim3(32, 16), 256, 0, stream>>>(attn, wT_o, b_o + l * 1024,
                                                        nullptr, h, 1024, 1024);
    k_rms<<<Mm, 256, 0, stream>>>(h, 1024, norm2_w + l * 1024, xn, 1024);
    // w_in + silu: 128x128 (R12 best), grid 16x44
    k_gemm<3, 128, 128><<<dim3(16, 44), 256, 0, stream>>>(xn, wT_in, b_in + l * 5632,
                                                          nullptr, gate, 5632, 1024);
    // w_out residual: 64x64, grid 32x16
    k_gemm<1, 64, 64><<<dim3(32, 16), 256, 0, stream>>>(gate, wT_out, b_out + l * 1024,
                                                        nullptr, h, 1024, 2816);
  }

  k_rms<<<Mm, 256, 0, stream>>>(h, 1024, norm_f_w, xn, 1024);
  {
    WJobs jbh;
    jbh.j[0] = { w_head, warena, 1024, 32000, 0, 8000 };
    k_wcvt_batch<<<8000, 256, 0, stream>>>(jbh, 1);
  }
  // head: 128x128 tiles (R12 best), grid 16x250 = 4000 blocks
  k_gemm<0, 128, 128><<<dim3(16, 250), 256, 0, stream>>>(xn, warena, b_head,
                                                         nullptr, (float*)d_out, 32000, 1024);
}

// Round 15
// 1027.231 us; speedup vs baseline: 1.0923x; 1.0205x over previous
//
#include <hip/hip_runtime.h>
#include <cstdint>
#include <cstddef>

typedef unsigned short u16;
typedef __attribute__((__ext_vector_type__(8))) __bf16 bf16x8;
typedef __attribute__((__ext_vector_type__(4))) float f32x4;
typedef __attribute__((__ext_vector_type__(8))) unsigned short u16x8;

#define DEVI __device__ __forceinline__

constexpr int Bb = 2, Ss = 1024, Dd = 1024, Hh = 16;
constexpr int Mm = Bb * Ss;
constexpr int QKD = 128;
constexpr float EPSF = 1.1920929e-07f;
constexpr float NEG = -1e30f;
constexpr float QSCALE = 0.10206207261596577f; // 1/sqrt(96)
constexpr float LOG1E4_16 = 9.210340371976184f / 16.f;

DEVI u16 f2b(float f) {
  union { float f; uint32_t u; } a; a.f = f;
  uint32_t r = a.u + 0x7FFFu + ((a.u >> 16) & 1u);
  return (u16)(r >> 16);
}
DEVI float b2f(u16 h) {
  union { uint32_t u; float f; } a; a.u = ((uint32_t)h) << 16; return a.f;
}

// ---------------- batched fp32 -> bf16 transposed weight conversion
struct WJob { const float* src; u16* dst; int K; int N; int perm; int ntiles; };
struct WJobs { WJob j[7]; };

__global__ __launch_bounds__(256) void k_wcvt_batch(WJobs jobs, int njobs) {
  int t = blockIdx.x;
  int ji = 0;
  while (ji < njobs - 1 && t >= jobs.j[ji].ntiles) { t -= jobs.j[ji].ntiles; ++ji; }
  const float* __restrict__ src = jobs.j[ji].src;
  u16* __restrict__ dst = jobs.j[ji].dst;
  const int K = jobs.j[ji].K, N = jobs.j[ji].N, perm = jobs.j[ji].perm;
  const int ktiles = K >> 6;
  const int bk = (t % ktiles) * 64;
  const int bn = (t / ktiles) * 64;
  __shared__ float ts[64][65];
  const int tid = threadIdx.x;
  {
    int c4 = tid & 15, r = tid >> 4;
    #pragma unroll
    for (int p = 0; p < 4; ++p) {
      int row = r + p * 16;
      int col = bn + c4 * 4;
      float4 v = make_float4(0.f, 0.f, 0.f, 0.f);
      if (col < N) v = *(const float4*)(src + (size_t)(bk + row) * N + col);
      ts[row][c4 * 4 + 0] = v.x; ts[row][c4 * 4 + 1] = v.y;
      ts[row][c4 * 4 + 2] = v.z; ts[row][c4 * 4 + 3] = v.w;
    }
  }
  __syncthreads();
  {
    int k8 = tid & 7, c = tid >> 3;
    #pragma unroll
    for (int p = 0; p < 2; ++p) {
      int cc = c + p * 32;
      int gcol = bn + cc;
      int row = perm ? ((gcol < 2816) ? (gcol * 2) : ((gcol - 2816) * 2 + 1)) : gcol;
      u16x8 o;
      #pragma unroll
      for (int q = 0; q < 8; ++q) o[q] = f2b(ts[k8 * 8 + q][cc]);
      *(u16x8*)(dst + (size_t)row * K + bk + k8 * 8) = o;
    }
  }
}

// ---------------- embedding gather
__global__ void k_embed(const int* __restrict__ tok, const float* __restrict__ emb,
                        float* __restrict__ h) {
  int m = blockIdx.x;
  int t = tok[m];
  const float4* src = (const float4*)(emb + (size_t)t * Dd);
  float4* dst = (float4*)(h + (size_t)m * Dd);
  dst[threadIdx.x] = src[threadIdx.x];
}

// ---------------- rmsnorm: f32 (stride inStride) -> bf16 (stride K)
__global__ void k_rms(const float* __restrict__ in, int inStride,
                      const float* __restrict__ w, u16* __restrict__ out, int K) {
  int m = blockIdx.x;
  const float* x = in + (size_t)m * inStride;
  float ss = 0.f;
  for (int i = threadIdx.x; i < K; i += 256) { float v = x[i]; ss += v * v; }
  #pragma unroll
  for (int off = 32; off; off >>= 1) ss += __shfl_xor(ss, off);
  __shared__ float red[4];
  if ((threadIdx.x & 63) == 0) red[threadIdx.x >> 6] = ss;
  __syncthreads();
  float r = rsqrtf((red[0] + red[1] + red[2] + red[3]) / (float)K + EPSF);
  for (int i = threadIdx.x; i < K; i += 256)
    out[(size_t)m * K + i] = f2b(x[i] * r * w[i]);
}

// ---------------- fused dual rmsnorm over ckvq: cols 0..255 -> ckvn, 384..767 -> qdn
__global__ void k_rms2(const float* __restrict__ in, const float* __restrict__ w1,
                       const float* __restrict__ w2, u16* __restrict__ out1,
                       u16* __restrict__ out2) {
  int m = blockIdx.x;
  const float* x = in + (size_t)m * 768;
  int tid = threadIdx.x;
  __shared__ float red[4];
  // part 1: 256 cols
  {
    float v = x[tid];
    float ss = v * v;
    #pragma unroll
    for (int off = 32; off; off >>= 1) ss += __shfl_xor(ss, off);
    if ((tid & 63) == 0) red[tid >> 6] = ss;
    __syncthreads();
    float r = rsqrtf((red[0] + red[1] + red[2] + red[3]) / 256.f + EPSF);
    out1[(size_t)m * 256 + tid] = f2b(v * r * w1[tid]);
    __syncthreads();
  }
  // part 2: 384 cols (384..767)
  {
    float v0 = x[384 + tid];
    float v1 = (tid < 128) ? x[640 + tid] : 0.f;
    float ss = v0 * v0 + v1 * v1;
    #pragma unroll
    for (int off = 32; off; off >>= 1) ss += __shfl_xor(ss, off);
    if ((tid & 63) == 0) red[tid >> 6] = ss;
    __syncthreads();
    float r = rsqrtf((red[0] + red[1] + red[2] + red[3]) / 384.f + EPSF);
    out2[(size_t)m * 384 + tid] = f2b(v0 * r * w2[tid]);
    if (tid < 128) out2[(size_t)m * 384 + 256 + tid] = f2b(v1 * r * w2[256 + tid]);
  }
}

// ---------------- build K only (rope cols 64..95 from ckvq; pad to 128)
__global__ void k_buildk(const u16* __restrict__ kv, const float* __restrict__ ckvq,
                         u16* __restrict__ Kb) {
  int s = blockIdx.x, bh = blockIdx.y;
  int b = bh >> 4, h = bh & 15;
  int d = threadIdx.x;
  int m = b * Ss + s;
  int j = d - 64;
  u16 kvv = 0;
  if (d < 64) kvv = kv[(size_t)m * 2048 + h * 128 + d];
  else if (d < 96) {
    float theta = __expf(-(float)(j & 15) * LOG1E4_16);
    float sn, cs;
    __sincosf((float)s * theta, &sn, &cs);
    const float* rr = ckvq + (size_t)m * 768 + 256;
    float x = rr[j], o = rr[j ^ 16];
    kvv = f2b(x * cs + ((j < 16) ? -o : o) * sn);
  }
  Kb[((size_t)bh * Ss + s) * QKD + d] = kvv;
}

// ---------------- build V^T (per head: [64][1024]), bf16 in -> bf16 out
__global__ void k_buildvt(const u16* __restrict__ kv, u16* __restrict__ Vt) {
  __shared__ u16 t[32][33];
  int bh = blockIdx.x, s0 = blockIdx.y * 32, d0 = blockIdx.z * 32;
  int b = bh >> 4, h = bh & 15;
  int tx = threadIdx.x, ty = threadIdx.y;
  #pragma unroll
  for (int i = ty; i < 32; i += 8) {
    int s = s0 + i, d = d0 + tx;
    t[i][tx] = kv[(size_t)(b * Ss + s) * 2048 + h * 128 + 64 + d];
  }
  __syncthreads();
  #pragma unroll
  for (int i = ty; i < 32; i += 8) {
    int d = d0 + i, s = s0 + tx;
    Vt[((size_t)bh * 64 + d) * Ss + s] = t[tx][i];
  }
}

#define GAS __attribute__((address_space(1)))
#define LAS __attribute__((address_space(3)))
DEVI void gll16(const void* g, void* l) {
  __builtin_amdgcn_global_load_lds((GAS const void*)g, (LAS void*)l, 16, 0, 0);
}
#define VMW(n) asm volatile("s_waitcnt vmcnt(" #n ")" ::: "memory")
#define FENCE asm volatile("" ::: "memory")

// ---------------- fused flash attention (causal), bf16 in/out
// grid (8 pairs, 32 bh), 256 thr. Block handles q-tiles {p, 15-p}: 17 K-steps.
// Q read directly from qf with rope applied in-register (partner d^16 lives at
// lane^32 since g=lane>>4 indexes the 8-elem chunk; angle uses per-lane row).
__global__ __launch_bounds__(256) void k_flash(
    const u16* __restrict__ qf, const u16* __restrict__ Kg,
    const u16* __restrict__ Vtg, u16* __restrict__ attn) {
  __shared__ u16 lK[2][64 * 128];
  __shared__ u16 lV[2][64 * 64];
  __shared__ u16 lP[4][16 * 64];
  const int tid = threadIdx.x;
  const int pair = blockIdx.x, bh = blockIdx.y;
  const int b = bh >> 4, h = bh & 15;
  const int lane = tid & 63, w = tid >> 6;
  const int g = lane >> 4, fr = lane & 15;
  const u16* Kh = Kg + (size_t)bh * Ss * QKD;
  const u16* Vh = Vtg + (size_t)bh * 64 * Ss;

  auto stageKV = [&](int buf, int kt) {
    int r = tid >> 4, c = tid & 15;
    #pragma unroll
    for (int gg = 0; gg < 4; ++gg) {
      int row = gg * 16 + r;
      const u16* src = Kh + (size_t)(kt * 64 + row) * QKD + ((c ^ (row & 7)) * 8);
      gll16(src, (u16*)lK[buf] + gg * 2048 + tid * 8);
    }
    int r2 = tid >> 3, c2 = tid & 7;
    #pragma unroll
    for (int gg = 0; gg < 2; ++gg) {
      int d = gg * 32 + r2;
      const u16* src = Vh + (size_t)d * Ss + kt * 64 + ((c2 ^ (d & 7)) * 8);
      gll16(src, (u16*)lV[buf] + gg * 2048 + tid * 8);
    }
  };

  for (int pass = 0; pass < 2; ++pass) {
    const int qt = pass ? (15 - pair) : pair;
    const int q0 = qt * 64;
    const int s_row = q0 + w * 16 + fr;
    const u16* qrow = qf + (size_t)(b * Ss + s_row) * 1536 + h * 96;
    // Q frags with inline rope + QSCALE (k4=3 is zero pad)
    bf16x8 af[4];
    {
      u16x8 r0 = *(const u16x8*)(qrow + g * 8);
      u16x8 r1 = *(const u16x8*)(qrow + 32 + g * 8);
      u16x8 r2 = *(const u16x8*)(qrow + 64 + g * 8);
      u16x8 a0, a1, a2, a3;
      #pragma unroll
      for (int q = 0; q < 8; ++q) {
        a0[q] = f2b(b2f(r0[q]) * QSCALE);
        a1[q] = f2b(b2f(r1[q]) * QSCALE);
        float x = b2f(r2[q]);
        float oth = __shfl_xor(x, 32);
        int jj = (g & 1) * 8 + q;
        float theta = __expf(-(float)jj * LOG1E4_16);
        float sn, cs;
        __sincosf((float)s_row * theta, &sn, &cs);
        float v = x * cs + ((g < 2) ? -oth : oth) * sn;
        a2[q] = f2b(v * QSCALE);
        a3[q] = 0;
      }
      af[0] = *(bf16x8*)&a0; af[1] = *(bf16x8*)&a1;
      af[2] = *(bf16x8*)&a2; af[3] = *(bf16x8*)&a3;
    }

    f32x4 acc_o[4] = {};
    float mrow = NEG, lrow = 0.f;

    stageKV(0, 0);

    for (int kt = 0; kt <= qt; ++kt) {
      const int cur = kt & 1;
      if (kt < qt) { stageKV(cur ^ 1, kt + 1); VMW(6); }
      else { VMW(0); }
      __builtin_amdgcn_s_barrier();
      FENCE;

      f32x4 accs[4] = {};
      #pragma unroll
      for (int j = 0; j < 4; ++j) {
        #pragma unroll
        for (int k4 = 0; k4 < 4; ++k4) {
          int row = j * 16 + fr;
          int ch = (k4 * 4 + g) ^ (row & 7);
          bf16x8 kf = *(const bf16x8*)&lK[cur][row * 128 + ch * 8];
          accs[j] = __builtin_amdgcn_mfma_f32_16x16x32_bf16(kf, af[k4], accs[j], 0, 0, 0);
        }
      }

      float p[16];
      float tmax = NEG;
      #pragma unroll
      for (int j = 0; j < 4; ++j)
        #pragma unroll
        for (int r = 0; r < 4; ++r) {
          float s = accs[j][r];
          int kloc = j * 16 + 4 * g + r;
          bool valid = (kt < qt) || (kloc <= w * 16 + fr);
          s = valid ? s : NEG;
          p[j * 4 + r] = s;
          tmax = fmaxf(tmax, s);
        }
      tmax = fmaxf(tmax, __shfl_xor(tmax, 16));
      tmax = fmaxf(tmax, __shfl_xor(tmax, 32));
      float mnew = fmaxf(mrow, tmax);
      float scale = __expf(mrow - mnew);
      float tsum = 0.f;
      #pragma unroll
      for (int i = 0; i < 16; ++i) { p[i] = __expf(p[i] - mnew); tsum += p[i]; }
      tsum += __shfl_xor(tsum, 16);
      tsum += __shfl_xor(tsum, 32);
      lrow = lrow * scale + tsum;
      mrow = mnew;

      #pragma unroll
      for (int j = 0; j < 4; ++j)
        #pragma unroll
        for (int t = 0; t < 2; ++t) {
          uint32_t u = (uint32_t)f2b(p[j * 4 + 2 * t]) |
                       ((uint32_t)f2b(p[j * 4 + 2 * t + 1]) << 16);
          int kp = 8 * j + 2 * g + t;
          int ch = kp >> 2, wi = kp & 3;
          ((uint32_t*)lP[w])[fr * 32 + ((ch ^ (fr & 7)) << 2) + wi] = u;
        }

      float sc_q[4];
      #pragma unroll
      for (int r = 0; r < 4; ++r) sc_q[r] = __shfl(scale, 4 * g + r);
      #pragma unroll
      for (int j2 = 0; j2 < 4; ++j2)
        #pragma unroll
        for (int r = 0; r < 4; ++r) acc_o[j2][r] *= sc_q[r];

      #pragma unroll
      for (int ksub = 0; ksub < 2; ++ksub) {
        int chp = (4 * ksub + g) ^ (fr & 7);
        bf16x8 pa = *(const bf16x8*)&((const u16*)lP[w])[fr * 64 + chp * 8];
        #pragma unroll
        for (int j2 = 0; j2 < 4; ++j2) {
          int d = j2 * 16 + fr;
          int chv = (ksub * 4 + g) ^ (d & 7);
          bf16x8 vf = *(const bf16x8*)&lV[cur][d * 64 + chv * 8];
          acc_o[j2] = __builtin_amdgcn_mfma_f32_16x16x32_bf16(pa, vf, acc_o[j2], 0, 0, 0);
        }
      }
      FENCE;
      __builtin_amdgcn_s_barrier();
      FENCE;
    }

    float li[4];
    #pragma unroll
    for (int r = 0; r < 4; ++r) li[r] = 1.f / __shfl(lrow, 4 * g + r);
    #pragma unroll
    for (int j2 = 0; j2 < 4; ++j2)
      #pragma unroll
      for (int r = 0; r < 4; ++r) {
        int q = q0 + w * 16 + 4 * g + r;
        int d = j2 * 16 + fr;
        attn[((size_t)(b * Ss) + q) * Dd + h * 64 + d] = f2b(acc_o[j2][r] * li[r]);
      }
  }
}

// ---------------- generic bf16 MFMA GEMM, BMxBN tiles, 256 thr (2x2 waves),
// chunk-XOR swizzle (0 conflicts), dbuf + prefetch + counted vmcnt.
// MODE 0: f32 C = acc+bias ; 1: f32 C += acc+bias ; 2: bf16 C = acc+bias ;
// MODE 3: silu-fused (pair-interleaved Bt): bf16 gate out [M][2816]
// MODE 4: f32 C = acc + dual-bias (cols 0..287 bias, 384..767 bias2)
template <int MODE, int BM, int BN, int MINW = 4>
__global__ __launch_bounds__(256, MINW) void k_gemm(
    const u16* __restrict__ A, const u16* __restrict__ Bt,
    const float* __restrict__ bias, const float* __restrict__ bias2,
    void* __restrict__ C, int N, int K) {
  constexpr int MI = BM / 32, NJ = BN / 32;
  constexpr int AL = BM / 64, BL = BN / 64;
  __shared__ u16 lA[2][BM * 32];
  __shared__ u16 lB[2][BN * 32];
  const int tid = threadIdx.x;
  const int gx = gridDim.x;
  const int nwg = gx * gridDim.y;
  const int f = blockIdx.y * gx + blockIdx.x;
  const int f2 = (f & 7) * (nwg >> 3) + (f >> 3);   // xcd swizzle, nwg%8==0
  const int bx = f2 % gx, by = f2 / gx;
  const long m0 = (long)bx * BM, n0 = (long)by * BN;
  const int lane = tid & 63, wid = tid >> 6;
  const int wm = (wid >> 1) * (BM / 2), wn = (wid & 1) * (BN / 2);
  const int fr = lane & 15, l4 = lane >> 4;
  const int sw = (fr >> 1) & 3;

  const int rs = tid >> 2;
  const int cs = ((tid & 3) ^ ((rs >> 1) & 3)) * 8;
  const u16* a0 = A + (m0 + rs) * (long)K + cs;
  const u16* b0 = Bt + (n0 + rs) * (long)K + cs;
  const long g64 = 64L * K;

  f32x4 acc[MI][NJ] = {};
  const int NT = K >> 5;

  auto stage = [&](int buf, int kk) {
    #pragma unroll
    for (int g = 0; g < AL; ++g)
      gll16(a0 + g * g64 + kk, (u16*)lA[buf] + g * 2048 + tid * 8);
    #pragma unroll
    for (int g = 0; g < BL; ++g)
      gll16(b0 + g * g64 + kk, (u16*)lB[buf] + g * 2048 + tid * 8);
  };

  stage(0, 0);

  for (int j = 0; j < NT; ++j) {
    const int cur = j & 1;
    const int kk1 = (j + 1) << 5;
    if (j + 1 < NT) {
      stage(cur ^ 1, kk1);
      if constexpr (AL + BL == 2) VMW(2);
      else if constexpr (AL + BL == 3) VMW(3);
      else if constexpr (AL + BL == 4) VMW(4);
      else if constexpr (AL + BL == 5) VMW(5);
      else VMW(6);
    } else {
      VMW(0);
    }
    __builtin_amdgcn_s_barrier();
    FENCE;
    bf16x8 af[MI], bfr[NJ];
    #pragma unroll
    for (int i = 0; i < MI; i++)
      af[i] = *(const bf16x8*)&lA[cur][(wm + i * 16 + fr) * 32 + ((l4 ^ sw) * 8)];
    #pragma unroll
    for (int jj = 0; jj < NJ; jj++)
      bfr[jj] = *(const bf16x8*)&lB[cur][(wn + jj * 16 + fr) * 32 + ((l4 ^ sw) * 8)];
    #pragma unroll
    for (int i = 0; i < MI; i++)
      #pragma unroll
      for (int jj = 0; jj < NJ; jj++)
        acc[i][jj] = __builtin_amdgcn_mfma_f32_16x16x32_bf16(af[i], bfr[jj], acc[i][jj], 0, 0, 0);
    FENCE;
    __builtin_amdgcn_s_barrier();
    FENCE;
  }

  const long r0 = m0 + wm + l4 * 4;
  const long c0 = n0 + wn + fr;
  if (MODE == 3) {
    u16* G = (u16*)C;
    #pragma unroll
    for (int j = 0; j < NJ; ++j) {
      long col = c0 + j * 16;
      int pcol = (int)((col & 1) ? (col >> 1) + 2816 : (col >> 1));
      float bs = bias[pcol];
      #pragma unroll
      for (int i = 0; i < MI; ++i)
        #pragma unroll
        for (int r = 0; r < 4; ++r) {
          float val = acc[i][j][r] + bs;
          float oth = __shfl_xor(val, 1);
          if (!(col & 1)) {
            float x = oth;
            float gv = val * x * (1.f / (1.f + __expf(-x)));
            G[(r0 + i * 16 + r) * 2816L + (col >> 1)] = f2b(gv);
          }
        }
    }
  } else {
    #pragma unroll
    for (int j = 0; j < NJ; ++j) {
      long col = c0 + j * 16;
      float bs;
      if (MODE == 4)
        bs = (col < 288) ? bias[col] : ((col >= 384) ? bias2[col - 384] : 0.f);
      else
        bs = bias[col];
      #pragma unroll
      for (int i = 0; i < MI; ++i)
        #pragma unroll
        for (int r = 0; r < 4; ++r) {
          long row = r0 + i * 16 + r;
          float val = acc[i][j][r] + bs;
          if (MODE == 0 || MODE == 4) ((float*)C)[row * N + col] = val;
          else if (MODE == 1) { float* p = (float*)C + row * N + col; *p += val; }
          else ((u16*)C)[row * N + col] = f2b(val);
        }
    }
  }
}

extern "C" void kernel_launch(void* const* d_in, const int* in_sizes, int n_in,
                              void* d_out, int out_size, void* d_ws, size_t ws_size,
                              hipStream_t stream) {
  (void)in_sizes; (void)n_in; (void)out_size; (void)ws_size;
  const int*   tokens    = (const int*)  d_in[0];
  const float* embed     = (const float*)d_in[1];
  const float* w_kv_down = (const float*)d_in[2];
  const float* b_kv_down = (const float*)d_in[3];
  const float* w_q_down  = (const float*)d_in[4];
  const float* b_q_down  = (const float*)d_in[5];
  const float* w_kv_up   = (const float*)d_in[6];
  const float* b_kv_up   = (const float*)d_in[7];
  const float* w_q_up    = (const float*)d_in[8];
  const float* b_q_up    = (const float*)d_in[9];
  const float* w_o       = (const float*)d_in[10];
  const float* b_o       = (const float*)d_in[11];
  const float* kv_norm_w = (const float*)d_in[12];
  const float* q_norm_w  = (const float*)d_in[13];
  const float* norm1_w   = (const float*)d_in[14];
  const float* norm2_w   = (const float*)d_in[15];
  const float* w_in      = (const float*)d_in[16];
  const float* b_in      = (const float*)d_in[17];
  const float* w_out     = (const float*)d_in[18];
  const float* b_out     = (const float*)d_in[19];
  const float* norm_f_w  = (const float*)d_in[20];
  const float* w_head    = (const float*)d_in[21];
  const float* b_head    = (const float*)d_in[22];

  char* base = (char*)d_ws;
  size_t off = 0;
  auto alloc = [&](size_t bytes) -> void* {
    void* p = base + off;
    off += (bytes + 255) & ~(size_t)255;
    return p;
  };
  u16* warena = (u16*)alloc((size_t)32000 * 1024 * 2);
  u16* wT_dq    = warena;                        // 768 x 1024
  u16* wT_kvup  = wT_dq   + 768 * 1024;          // 2048 x 256
  u16* wT_qup   = wT_kvup + 2048 * 256;          // 1536 x 384
  u16* wT_o     = wT_qup  + 1536 * 384;          // 1024 x 1024
  u16* wT_in    = wT_o    + 1024 * 1024;         // 5632 x 1024 (pair-interleaved)
  u16* wT_out   = wT_in   + 5632 * 1024;         // 1024 x 2816

  float* h     = (float*)alloc((size_t)Mm * 1024 * 4);
  u16*   xn    = (u16*)  alloc((size_t)Mm * 1024 * 2);
  float* ckvq  = (float*)alloc((size_t)Mm * 768 * 4);
  u16*   ckvn  = (u16*)  alloc((size_t)Mm * 256 * 2);
  u16*   kv    = (u16*)  alloc((size_t)Mm * 2048 * 2);
  u16*   qdn   = (u16*)  alloc((size_t)Mm * 384 * 2);
  u16*   qf    = (u16*)  alloc((size_t)Mm * 1536 * 2);
  u16*   Kb    = (u16*)  alloc((size_t)32 * 1024 * QKD * 2);
  u16*   Vt    = (u16*)  alloc((size_t)32 * 64 * 1024 * 2);
  u16*   attn  = (u16*)  alloc((size_t)Mm * 1024 * 2);
  u16*   gate  = (u16*)  alloc((size_t)Mm * 2816 * 2);

  dim3 tb(32, 8);

  k_embed<<<Mm, 256, 0, stream>>>(tokens, embed, h);

  for (int l = 0; l < 4; l++) {
    WJobs jb;
    jb.j[0] = { w_kv_down + (size_t)l * 1024 * 288,  wT_dq,              1024, 288,  0, 96 };
    jb.j[1] = { w_q_down  + (size_t)l * 1024 * 384,  wT_dq + 384 * 1024, 1024, 384,  0, 96 };
    jb.j[2] = { w_kv_up   + (size_t)l * 256 * 2048,  wT_kvup,            256,  2048, 0, 128 };
    jb.j[3] = { w_q_up    + (size_t)l * 384 * 1536,  wT_qup,             384,  1536, 0, 144 };
    jb.j[4] = { w_o       + (size_t)l * 1024 * 1024, wT_o,               1024, 1024, 0, 256 };
    jb.j[5] = { w_in      + (size_t)l * 1024 * 5632, wT_in,              1024, 5632, 1, 1408 };
    jb.j[6] = { w_out     + (size_t)l * 2816 * 1024, wT_out,             2816, 1024, 0, 704 };
    k_wcvt_batch<<<2832, 256, 0, stream>>>(jb, 7);

    k_rms<<<Mm, 256, 0, stream>>>(h, 1024, norm1_w + l * 1024, xn, 1024);
    // fused kv_down+q_down with dual bias (MODE 4): 64x64 tiles, grid 32x12
    k_gemm<4, 64, 64><<<dim3(32, 12), 256, 0, stream>>>(xn, wT_dq, b_kv_down + l * 288,
                                                        b_q_down + l * 384, ckvq, 768, 1024);
    // fused dual rmsnorm (ckvn + qdn)
    k_rms2<<<Mm, 256, 0, stream>>>(ckvq, kv_norm_w + l * 256, q_norm_w + l * 384,
                                   ckvn, qdn);
    // kv_up -> bf16, 64x128 tiles, grid 32x16
    k_gemm<2, 64, 128><<<dim3(32, 16), 256, 0, stream>>>(ckvn, wT_kvup, b_kv_up + l * 2048,
                                                         nullptr, kv, 2048, 256);
    // q_up -> bf16 (MODE 2): 64x64, grid 32x24
    k_gemm<2, 64, 64><<<dim3(32, 24), 256, 0, stream>>>(qdn, wT_qup, b_q_up + l * 1536,
                                                        nullptr, qf, 1536, 384);
    k_buildk<<<dim3(Ss, 32), 128, 0, stream>>>(kv, ckvq, Kb);
    k_buildvt<<<dim3(32, 32, 2), tb, 0, stream>>>(kv, Vt);
    // flash: pair-balanced, Q-rope inlined (reads qf directly), grid 8x32
    k_flash<<<dim3(8, 32), 256, 0, stream>>>(qf, Kb, Vt, attn);
    // w_o residual: 64x64, grid 32x16
    k_gemm<1, 64, 64><<<dim3(32, 16), 256, 0, stream>>>(attn, wT_o, b_o + l * 1024,
                                                        nullptr, h, 1024, 1024);
    k_rms<<<Mm, 256, 0, stream>>>(h, 1024, norm2_w + l * 1024, xn, 1024);
    // w_in + silu: 128x128, grid 16x44
    k_gemm<3, 128, 128><<<dim3(16, 44), 256, 0, stream>>>(xn, wT_in, b_in + l * 5632,
                                                          nullptr, gate, 5632, 1024);
    // w_out residual: 64x64, grid 32x16
    k_gemm<1, 64, 64><<<dim3(32, 16), 256, 0, stream>>>(gate, wT_out, b_out + l * 1024,
                                                        nullptr, h, 1024, 2816);
  }

  k_rms<<<Mm, 256, 0, stream>>>(h, 1024, norm_f_w, xn, 1024);
  {
    WJobs jbh;
    jbh.j[0] = { w_head, warena, 1024, 32000, 0, 8000 };
    k_wcvt_batch<<<8000, 256, 0, stream>>>(jbh, 1);
  }
  // head: 128x128 tiles, grid 16x250 = 4000 blocks
  k_gemm<0, 128, 128><<<dim3(16, 250), 256, 0, stream>>>(xn, warena, b_head,
                                                         nullptr, (float*)d_out, 32000, 1024);
}

// Round 16
// 985.842 us; speedup vs baseline: 1.1381x; 1.0420x over previous
//
#include <hip/hip_runtime.h>
#include <cstdint>
#include <cstddef>

typedef unsigned short u16;
typedef __attribute__((__ext_vector_type__(8))) __bf16 bf16x8;
typedef __attribute__((__ext_vector_type__(4))) float f32x4;
typedef __attribute__((__ext_vector_type__(8))) unsigned short u16x8;

#define DEVI __device__ __forceinline__

constexpr int Bb = 2, Ss = 1024, Dd = 1024, Hh = 16;
constexpr int Mm = Bb * Ss;
constexpr int QKD = 128;
constexpr float EPSF = 1.1920929e-07f;
constexpr float NEG = -1e30f;
constexpr float QSCALE = 0.10206207261596577f; // 1/sqrt(96)
constexpr float LOG1E4_16 = 9.210340371976184f / 16.f;

DEVI u16 f2b(float f) {
  union { float f; uint32_t u; } a; a.f = f;
  uint32_t r = a.u + 0x7FFFu + ((a.u >> 16) & 1u);
  return (u16)(r >> 16);
}
DEVI float b2f(u16 h) {
  union { uint32_t u; float f; } a; a.u = ((uint32_t)h) << 16; return a.f;
}

// ---------------- batched fp32 -> bf16 transposed weight conversion
// Multi-layer: blockIdx.x -> (layer, tile); per-job src stride, common dst stride.
struct WJob { const float* src; u16* dst; long src_lstride; int K; int N; int perm; int ntiles; };
struct WJobs { WJob j[7]; };

__global__ __launch_bounds__(256) void k_wcvt_batch(WJobs jobs, int njobs,
                                                    int tiles_per_layer, long dst_lstride) {
  int bt = blockIdx.x;
  int layer = bt / tiles_per_layer;
  int t = bt - layer * tiles_per_layer;
  int ji = 0;
  while (ji < njobs - 1 && t >= jobs.j[ji].ntiles) { t -= jobs.j[ji].ntiles; ++ji; }
  const float* __restrict__ src = jobs.j[ji].src + (size_t)layer * jobs.j[ji].src_lstride;
  u16* __restrict__ dst = jobs.j[ji].dst + (size_t)layer * dst_lstride;
  const int K = jobs.j[ji].K, N = jobs.j[ji].N, perm = jobs.j[ji].perm;
  const int ktiles = K >> 6;
  const int bk = (t % ktiles) * 64;
  const int bn = (t / ktiles) * 64;
  __shared__ float ts[64][65];
  const int tid = threadIdx.x;
  {
    int c4 = tid & 15, r = tid >> 4;
    #pragma unroll
    for (int p = 0; p < 4; ++p) {
      int row = r + p * 16;
      int col = bn + c4 * 4;
      float4 v = make_float4(0.f, 0.f, 0.f, 0.f);
      if (col < N) v = *(const float4*)(src + (size_t)(bk + row) * N + col);
      ts[row][c4 * 4 + 0] = v.x; ts[row][c4 * 4 + 1] = v.y;
      ts[row][c4 * 4 + 2] = v.z; ts[row][c4 * 4 + 3] = v.w;
    }
  }
  __syncthreads();
  {
    int k8 = tid & 7, c = tid >> 3;
    #pragma unroll
    for (int p = 0; p < 2; ++p) {
      int cc = c + p * 32;
      int gcol = bn + cc;
      int row = perm ? ((gcol < 2816) ? (gcol * 2) : ((gcol - 2816) * 2 + 1)) : gcol;
      u16x8 o;
      #pragma unroll
      for (int q = 0; q < 8; ++q) o[q] = f2b(ts[k8 * 8 + q][cc]);
      *(u16x8*)(dst + (size_t)row * K + bk + k8 * 8) = o;
    }
  }
}

// ---------------- embedding gather
__global__ void k_embed(const int* __restrict__ tok, const float* __restrict__ emb,
                        float* __restrict__ h) {
  int m = blockIdx.x;
  int t = tok[m];
  const float4* src = (const float4*)(emb + (size_t)t * Dd);
  float4* dst = (float4*)(h + (size_t)m * Dd);
  dst[threadIdx.x] = src[threadIdx.x];
}

// ---------------- rmsnorm: f32 (stride inStride) -> bf16 (stride K)
__global__ void k_rms(const float* __restrict__ in, int inStride,
                      const float* __restrict__ w, u16* __restrict__ out, int K) {
  int m = blockIdx.x;
  const float* x = in + (size_t)m * inStride;
  float ss = 0.f;
  for (int i = threadIdx.x; i < K; i += 256) { float v = x[i]; ss += v * v; }
  #pragma unroll
  for (int off = 32; off; off >>= 1) ss += __shfl_xor(ss, off);
  __shared__ float red[4];
  if ((threadIdx.x & 63) == 0) red[threadIdx.x >> 6] = ss;
  __syncthreads();
  float r = rsqrtf((red[0] + red[1] + red[2] + red[3]) / (float)K + EPSF);
  for (int i = threadIdx.x; i < K; i += 256)
    out[(size_t)m * K + i] = f2b(x[i] * r * w[i]);
}

// ---------------- fused dual rmsnorm over ckvq: cols 0..255 -> ckvn, 384..767 -> qdn
__global__ void k_rms2(const float* __restrict__ in, const float* __restrict__ w1,
                       const float* __restrict__ w2, u16* __restrict__ out1,
                       u16* __restrict__ out2) {
  int m = blockIdx.x;
  const float* x = in + (size_t)m * 768;
  int tid = threadIdx.x;
  __shared__ float red[4];
  {
    float v = x[tid];
    float ss = v * v;
    #pragma unroll
    for (int off = 32; off; off >>= 1) ss += __shfl_xor(ss, off);
    if ((tid & 63) == 0) red[tid >> 6] = ss;
    __syncthreads();
    float r = rsqrtf((red[0] + red[1] + red[2] + red[3]) / 256.f + EPSF);
    out1[(size_t)m * 256 + tid] = f2b(v * r * w1[tid]);
    __syncthreads();
  }
  {
    float v0 = x[384 + tid];
    float v1 = (tid < 128) ? x[640 + tid] : 0.f;
    float ss = v0 * v0 + v1 * v1;
    #pragma unroll
    for (int off = 32; off; off >>= 1) ss += __shfl_xor(ss, off);
    if ((tid & 63) == 0) red[tid >> 6] = ss;
    __syncthreads();
    float r = rsqrtf((red[0] + red[1] + red[2] + red[3]) / 384.f + EPSF);
    out2[(size_t)m * 384 + tid] = f2b(v0 * r * w2[tid]);
    if (tid < 128) out2[(size_t)m * 384 + 256 + tid] = f2b(v1 * r * w2[256 + tid]);
  }
}

// ---------------- merged build K + build V^T.
// grid (32 bh, 32 s-chunk, 3): z<2 -> V^T transpose tile (d0=z*32); z=2 -> K build.
__global__ void k_buildkv(const u16* __restrict__ kv, const float* __restrict__ ckvq,
                          u16* __restrict__ Kb, u16* __restrict__ Vt) {
  int bh = blockIdx.x, chunk = blockIdx.y, role = blockIdx.z;
  int b = bh >> 4, h = bh & 15;
  if (role < 2) {
    __shared__ u16 t[32][33];
    int tx = threadIdx.x & 31, ty = threadIdx.x >> 5;
    int s0 = chunk * 32, d0 = role * 32;
    #pragma unroll
    for (int i = ty; i < 32; i += 8)
      t[i][tx] = kv[(size_t)(b * Ss + s0 + i) * 2048 + h * 128 + 64 + d0 + tx];
    __syncthreads();
    #pragma unroll
    for (int i = ty; i < 32; i += 8)
      Vt[((size_t)bh * 64 + d0 + i) * Ss + s0 + tx] = t[tx][i];
  } else {
    int idx = threadIdx.x;
    int d = idx & 127, r0 = idx >> 7;
    #pragma unroll
    for (int it = 0; it < 16; ++it) {
      int s = chunk * 32 + it * 2 + r0;
      int m = b * Ss + s;
      u16 kvv = 0;
      if (d < 64) kvv = kv[(size_t)m * 2048 + h * 128 + d];
      else if (d < 96) {
        int j = d - 64;
        float theta = __expf(-(float)(j & 15) * LOG1E4_16);
        float sn, cs;
        __sincosf((float)s * theta, &sn, &cs);
        const float* rr = ckvq + (size_t)m * 768 + 256;
        float x = rr[j], o = rr[j ^ 16];
        kvv = f2b(x * cs + ((j < 16) ? -o : o) * sn);
      }
      Kb[((size_t)bh * Ss + s) * QKD + d] = kvv;
    }
  }
}

#define GAS __attribute__((address_space(1)))
#define LAS __attribute__((address_space(3)))
DEVI void gll16(const void* g, void* l) {
  __builtin_amdgcn_global_load_lds((GAS const void*)g, (LAS void*)l, 16, 0, 0);
}
#define VMW(n) asm volatile("s_waitcnt vmcnt(" #n ")" ::: "memory")
#define FENCE asm volatile("" ::: "memory")

// ---------------- fused flash attention (causal), bf16 in/out
__global__ __launch_bounds__(256) void k_flash(
    const u16* __restrict__ qf, const u16* __restrict__ Kg,
    const u16* __restrict__ Vtg, u16* __restrict__ attn) {
  __shared__ u16 lK[2][64 * 128];
  __shared__ u16 lV[2][64 * 64];
  __shared__ u16 lP[4][16 * 64];
  const int tid = threadIdx.x;
  const int pair = blockIdx.x, bh = blockIdx.y;
  const int b = bh >> 4, h = bh & 15;
  const int lane = tid & 63, w = tid >> 6;
  const int g = lane >> 4, fr = lane & 15;
  const u16* Kh = Kg + (size_t)bh * Ss * QKD;
  const u16* Vh = Vtg + (size_t)bh * 64 * Ss;

  auto stageKV = [&](int buf, int kt) {
    int r = tid >> 4, c = tid & 15;
    #pragma unroll
    for (int gg = 0; gg < 4; ++gg) {
      int row = gg * 16 + r;
      const u16* src = Kh + (size_t)(kt * 64 + row) * QKD + ((c ^ (row & 7)) * 8);
      gll16(src, (u16*)lK[buf] + gg * 2048 + tid * 8);
    }
    int r2 = tid >> 3, c2 = tid & 7;
    #pragma unroll
    for (int gg = 0; gg < 2; ++gg) {
      int d = gg * 32 + r2;
      const u16* src = Vh + (size_t)d * Ss + kt * 64 + ((c2 ^ (d & 7)) * 8);
      gll16(src, (u16*)lV[buf] + gg * 2048 + tid * 8);
    }
  };

  for (int pass = 0; pass < 2; ++pass) {
    const int qt = pass ? (15 - pair) : pair;
    const int q0 = qt * 64;
    const int s_row = q0 + w * 16 + fr;
    const u16* qrow = qf + (size_t)(b * Ss + s_row) * 1536 + h * 96;
    bf16x8 af[4];
    {
      u16x8 r0 = *(const u16x8*)(qrow + g * 8);
      u16x8 r1 = *(const u16x8*)(qrow + 32 + g * 8);
      u16x8 r2 = *(const u16x8*)(qrow + 64 + g * 8);
      u16x8 a0, a1, a2, a3;
      #pragma unroll
      for (int q = 0; q < 8; ++q) {
        a0[q] = f2b(b2f(r0[q]) * QSCALE);
        a1[q] = f2b(b2f(r1[q]) * QSCALE);
        float x = b2f(r2[q]);
        float oth = __shfl_xor(x, 32);
        int jj = (g & 1) * 8 + q;
        float theta = __expf(-(float)jj * LOG1E4_16);
        float sn, cs;
        __sincosf((float)s_row * theta, &sn, &cs);
        float v = x * cs + ((g < 2) ? -oth : oth) * sn;
        a2[q] = f2b(v * QSCALE);
        a3[q] = 0;
      }
      af[0] = *(bf16x8*)&a0; af[1] = *(bf16x8*)&a1;
      af[2] = *(bf16x8*)&a2; af[3] = *(bf16x8*)&a3;
    }

    f32x4 acc_o[4] = {};
    float mrow = NEG, lrow = 0.f;

    stageKV(0, 0);

    for (int kt = 0; kt <= qt; ++kt) {
      const int cur = kt & 1;
      if (kt < qt) { stageKV(cur ^ 1, kt + 1); VMW(6); }
      else { VMW(0); }
      __builtin_amdgcn_s_barrier();
      FENCE;

      f32x4 accs[4] = {};
      #pragma unroll
      for (int j = 0; j < 4; ++j) {
        #pragma unroll
        for (int k4 = 0; k4 < 4; ++k4) {
          int row = j * 16 + fr;
          int ch = (k4 * 4 + g) ^ (row & 7);
          bf16x8 kf = *(const bf16x8*)&lK[cur][row * 128 + ch * 8];
          accs[j] = __builtin_amdgcn_mfma_f32_16x16x32_bf16(kf, af[k4], accs[j], 0, 0, 0);
        }
      }

      float p[16];
      float tmax = NEG;
      #pragma unroll
      for (int j = 0; j < 4; ++j)
        #pragma unroll
        for (int r = 0; r < 4; ++r) {
          float s = accs[j][r];
          int kloc = j * 16 + 4 * g + r;
          bool valid = (kt < qt) || (kloc <= w * 16 + fr);
          s = valid ? s : NEG;
          p[j * 4 + r] = s;
          tmax = fmaxf(tmax, s);
        }
      tmax = fmaxf(tmax, __shfl_xor(tmax, 16));
      tmax = fmaxf(tmax, __shfl_xor(tmax, 32));
      float mnew = fmaxf(mrow, tmax);
      float scale = __expf(mrow - mnew);
      float tsum = 0.f;
      #pragma unroll
      for (int i = 0; i < 16; ++i) { p[i] = __expf(p[i] - mnew); tsum += p[i]; }
      tsum += __shfl_xor(tsum, 16);
      tsum += __shfl_xor(tsum, 32);
      lrow = lrow * scale + tsum;
      mrow = mnew;

      #pragma unroll
      for (int j = 0; j < 4; ++j)
        #pragma unroll
        for (int t = 0; t < 2; ++t) {
          uint32_t u = (uint32_t)f2b(p[j * 4 + 2 * t]) |
                       ((uint32_t)f2b(p[j * 4 + 2 * t + 1]) << 16);
          int kp = 8 * j + 2 * g + t;
          int ch = kp >> 2, wi = kp & 3;
          ((uint32_t*)lP[w])[fr * 32 + ((ch ^ (fr & 7)) << 2) + wi] = u;
        }

      float sc_q[4];
      #pragma unroll
      for (int r = 0; r < 4; ++r) sc_q[r] = __shfl(scale, 4 * g + r);
      #pragma unroll
      for (int j2 = 0; j2 < 4; ++j2)
        #pragma unroll
        for (int r = 0; r < 4; ++r) acc_o[j2][r] *= sc_q[r];

      #pragma unroll
      for (int ksub = 0; ksub < 2; ++ksub) {
        int chp = (4 * ksub + g) ^ (fr & 7);
        bf16x8 pa = *(const bf16x8*)&((const u16*)lP[w])[fr * 64 + chp * 8];
        #pragma unroll
        for (int j2 = 0; j2 < 4; ++j2) {
          int d = j2 * 16 + fr;
          int chv = (ksub * 4 + g) ^ (d & 7);
          bf16x8 vf = *(const bf16x8*)&lV[cur][d * 64 + chv * 8];
          acc_o[j2] = __builtin_amdgcn_mfma_f32_16x16x32_bf16(pa, vf, acc_o[j2], 0, 0, 0);
        }
      }
      FENCE;
      __builtin_amdgcn_s_barrier();
      FENCE;
    }

    float li[4];
    #pragma unroll
    for (int r = 0; r < 4; ++r) li[r] = 1.f / __shfl(lrow, 4 * g + r);
    #pragma unroll
    for (int j2 = 0; j2 < 4; ++j2)
      #pragma unroll
      for (int r = 0; r < 4; ++r) {
        int q = q0 + w * 16 + 4 * g + r;
        int d = j2 * 16 + fr;
        attn[((size_t)(b * Ss) + q) * Dd + h * 64 + d] = f2b(acc_o[j2][r] * li[r]);
      }
  }
}

// ---------------- generic bf16 MFMA GEMM core (swizzle computed by caller)
// MODE 0: f32 C = acc+bias ; 1: f32 C += acc+bias ; 2: bf16 C = acc+bias ;
// MODE 3: silu-fused (pair-interleaved Bt): bf16 gate out [M][2816]
// MODE 4: f32 C = acc + dual-bias (cols 0..287 bias, 384..767 bias2)
template <int MODE, int BM, int BN>
DEVI void gemm_core(const u16* __restrict__ A, const u16* __restrict__ Bt,
                    const float* __restrict__ bias, const float* __restrict__ bias2,
                    void* __restrict__ C, int N, int K, int bx, int by,
                    u16* lA, u16* lB) {
  constexpr int MI = BM / 32, NJ = BN / 32;
  constexpr int AL = BM / 64, BL = BN / 64;
  constexpr int ASZ = BM * 32, BSZ = BN * 32;
  const int tid = threadIdx.x;
  const long m0 = (long)bx * BM, n0 = (long)by * BN;
  const int lane = tid & 63, wid = tid >> 6;
  const int wm = (wid >> 1) * (BM / 2), wn = (wid & 1) * (BN / 2);
  const int fr = lane & 15, l4 = lane >> 4;
  const int sw = (fr >> 1) & 3;

  const int rs = tid >> 2;
  const int cs = ((tid & 3) ^ ((rs >> 1) & 3)) * 8;
  const u16* a0 = A + (m0 + rs) * (long)K + cs;
  const u16* b0 = Bt + (n0 + rs) * (long)K + cs;
  const long g64 = 64L * K;

  f32x4 acc[MI][NJ] = {};
  const int NT = K >> 5;

  auto stage = [&](int buf, int kk) {
    #pragma unroll
    for (int g = 0; g < AL; ++g)
      gll16(a0 + g * g64 + kk, lA + buf * ASZ + g * 2048 + tid * 8);
    #pragma unroll
    for (int g = 0; g < BL; ++g)
      gll16(b0 + g * g64 + kk, lB + buf * BSZ + g * 2048 + tid * 8);
  };

  stage(0, 0);

  for (int j = 0; j < NT; ++j) {
    const int cur = j & 1;
    const int kk1 = (j + 1) << 5;
    if (j + 1 < NT) {
      stage(cur ^ 1, kk1);
      if constexpr (AL + BL == 2) VMW(2);
      else if constexpr (AL + BL == 3) VMW(3);
      else if constexpr (AL + BL == 4) VMW(4);
      else if constexpr (AL + BL == 5) VMW(5);
      else VMW(6);
    } else {
      VMW(0);
    }
    __builtin_amdgcn_s_barrier();
    FENCE;
    bf16x8 af[MI], bfr[NJ];
    #pragma unroll
    for (int i = 0; i < MI; i++)
      af[i] = *(const bf16x8*)&lA[cur * ASZ + (wm + i * 16 + fr) * 32 + ((l4 ^ sw) * 8)];
    #pragma unroll
    for (int jj = 0; jj < NJ; jj++)
      bfr[jj] = *(const bf16x8*)&lB[cur * BSZ + (wn + jj * 16 + fr) * 32 + ((l4 ^ sw) * 8)];
    #pragma unroll
    for (int i = 0; i < MI; i++)
      #pragma unroll
      for (int jj = 0; jj < NJ; jj++)
        acc[i][jj] = __builtin_amdgcn_mfma_f32_16x16x32_bf16(af[i], bfr[jj], acc[i][jj], 0, 0, 0);
    FENCE;
    __builtin_amdgcn_s_barrier();
    FENCE;
  }

  const long r0 = m0 + wm + l4 * 4;
  const long c0 = n0 + wn + fr;
  if (MODE == 3) {
    u16* G = (u16*)C;
    #pragma unroll
    for (int j = 0; j < NJ; ++j) {
      long col = c0 + j * 16;
      int pcol = (int)((col & 1) ? (col >> 1) + 2816 : (col >> 1));
      float bs = bias[pcol];
      #pragma unroll
      for (int i = 0; i < MI; ++i)
        #pragma unroll
        for (int r = 0; r < 4; ++r) {
          float val = acc[i][j][r] + bs;
          float oth = __shfl_xor(val, 1);
          if (!(col & 1)) {
            float x = oth;
            float gv = val * x * (1.f / (1.f + __expf(-x)));
            G[(r0 + i * 16 + r) * 2816L + (col >> 1)] = f2b(gv);
          }
        }
    }
  } else {
    #pragma unroll
    for (int j = 0; j < NJ; ++j) {
      long col = c0 + j * 16;
      float bs;
      if (MODE == 4)
        bs = (col < 288) ? bias[col] : ((col >= 384) ? bias2[col - 384] : 0.f);
      else
        bs = bias[col];
      #pragma unroll
      for (int i = 0; i < MI; ++i)
        #pragma unroll
        for (int r = 0; r < 4; ++r) {
          long row = r0 + i * 16 + r;
          float val = acc[i][j][r] + bs;
          if (MODE == 0 || MODE == 4) ((float*)C)[row * N + col] = val;
          else if (MODE == 1) { float* p = (float*)C + row * N + col; *p += val; }
          else ((u16*)C)[row * N + col] = f2b(val);
        }
    }
  }
}

template <int MODE, int BM, int BN, int MINW = 4>
__global__ __launch_bounds__(256, MINW) void k_gemm(
    const u16* __restrict__ A, const u16* __restrict__ Bt,
    const float* __restrict__ bias, const float* __restrict__ bias2,
    void* __restrict__ C, int N, int K) {
  __shared__ u16 lA[2 * BM * 32];
  __shared__ u16 lB[2 * BN * 32];
  const int gx = gridDim.x;
  const int nwg = gx * gridDim.y;
  const int f = blockIdx.y * gx + blockIdx.x;
  const int f2 = (f & 7) * (nwg >> 3) + (f >> 3);   // xcd swizzle, nwg%8==0
  const int bx = f2 % gx, by = f2 / gx;
  gemm_core<MODE, BM, BN>(A, Bt, bias, bias2, C, N, K, bx, by, lA, lB);
}

// two independent <2,64,128> GEMMs in one launch (z selects), per-z gy guard
__global__ __launch_bounds__(256, 4) void k_gemm_pair(
    const u16* A0, const u16* Bt0, const float* b0, void* C0, int N0, int K0, int gy0,
    const u16* A1, const u16* Bt1, const float* b1, void* C1, int N1, int K1, int gy1) {
  __shared__ u16 lA[2 * 64 * 32];
  __shared__ u16 lB[2 * 128 * 32];
  const int z = blockIdx.z;
  const int gy = z ? gy1 : gy0;
  if ((int)blockIdx.y >= gy) return;
  const int gx = gridDim.x;
  const int nwg = gx * gy;                 // 512 / 384, both %8==0
  const int f = blockIdx.y * gx + blockIdx.x;
  const int f2 = (f & 7) * (nwg >> 3) + (f >> 3);
  const int bx = f2 % gx, by = f2 / gx;
  if (z) gemm_core<2, 64, 128>(A1, Bt1, b1, nullptr, C1, N1, K1, bx, by, lA, lB);
  else   gemm_core<2, 64, 128>(A0, Bt0, b0, nullptr, C0, N0, K0, bx, by, lA, lB);
}

extern "C" void kernel_launch(void* const* d_in, const int* in_sizes, int n_in,
                              void* d_out, int out_size, void* d_ws, size_t ws_size,
                              hipStream_t stream) {
  (void)in_sizes; (void)n_in; (void)out_size; (void)ws_size;
  const int*   tokens    = (const int*)  d_in[0];
  const float* embed     = (const float*)d_in[1];
  const float* w_kv_down = (const float*)d_in[2];
  const float* b_kv_down = (const float*)d_in[3];
  const float* w_q_down  = (const float*)d_in[4];
  const float* b_q_down  = (const float*)d_in[5];
  const float* w_kv_up   = (const float*)d_in[6];
  const float* b_kv_up   = (const float*)d_in[7];
  const float* w_q_up    = (const float*)d_in[8];
  const float* b_q_up    = (const float*)d_in[9];
  const float* w_o       = (const float*)d_in[10];
  const float* b_o       = (const float*)d_in[11];
  const float* kv_norm_w = (const float*)d_in[12];
  const float* q_norm_w  = (const float*)d_in[13];
  const float* norm1_w   = (const float*)d_in[14];
  const float* norm2_w   = (const float*)d_in[15];
  const float* w_in      = (const float*)d_in[16];
  const float* b_in      = (const float*)d_in[17];
  const float* w_out     = (const float*)d_in[18];
  const float* b_out     = (const float*)d_in[19];
  const float* norm_f_w  = (const float*)d_in[20];
  const float* w_head    = (const float*)d_in[21];
  const float* b_head    = (const float*)d_in[22];

  char* base = (char*)d_ws;
  size_t off = 0;
  auto alloc = [&](size_t bytes) -> void* {
    void* p = base + off;
    off += (bytes + 255) & ~(size_t)255;
    return p;
  };
  // per-layer weight slot layout (elements)
  const long O_DQ = 0, O_KVUP = 786432, O_QUP = 1310720, O_O = 1900544,
             O_IN = 2949120, O_OUT = 8716288, LSLOT = 11599872;
  u16* warena = (u16*)alloc((size_t)4 * LSLOT * 2);   // 4 layers; head aliases base later

  float* h     = (float*)alloc((size_t)Mm * 1024 * 4);
  u16*   xn    = (u16*)  alloc((size_t)Mm * 1024 * 2);
  float* ckvq  = (float*)alloc((size_t)Mm * 768 * 4);
  u16*   ckvn  = (u16*)  alloc((size_t)Mm * 256 * 2);
  u16*   kv    = (u16*)  alloc((size_t)Mm * 2048 * 2);
  u16*   qdn   = (u16*)  alloc((size_t)Mm * 384 * 2);
  u16*   qf    = (u16*)  alloc((size_t)Mm * 1536 * 2);
  u16*   Kb    = (u16*)  alloc((size_t)32 * 1024 * QKD * 2);
  u16*   Vt    = (u16*)  alloc((size_t)32 * 64 * 1024 * 2);
  u16*   attn  = (u16*)  alloc((size_t)Mm * 1024 * 2);
  u16*   gate  = (u16*)  alloc((size_t)Mm * 2816 * 2);

  k_embed<<<Mm, 256, 0, stream>>>(tokens, embed, h);

  // all 4 layers' weight conversion in one launch (2832 tiles/layer)
  {
    WJobs jb;
    jb.j[0] = { w_kv_down, warena + O_DQ,              1024L * 288,  1024, 288,  0, 96 };
    jb.j[1] = { w_q_down,  warena + O_DQ + 384 * 1024, 1024L * 384,  1024, 384,  0, 96 };
    jb.j[2] = { w_kv_up,   warena + O_KVUP,            256L * 2048,  256,  2048, 0, 128 };
    jb.j[3] = { w_q_up,    warena + O_QUP,             384L * 1536,  384,  1536, 0, 144 };
    jb.j[4] = { w_o,       warena + O_O,               1024L * 1024, 1024, 1024, 0, 256 };
    jb.j[5] = { w_in,      warena + O_IN,              1024L * 5632, 1024, 5632, 1, 1408 };
    jb.j[6] = { w_out,     warena + O_OUT,             2816L * 1024, 2816, 1024, 0, 704 };
    k_wcvt_batch<<<4 * 2832, 256, 0, stream>>>(jb, 7, 2832, LSLOT);
  }

  for (int l = 0; l < 4; l++) {
    u16* wl = warena + (size_t)l * LSLOT;
    u16* wT_dq  = wl + O_DQ;
    u16* wT_kvup = wl + O_KVUP;
    u16* wT_qup = wl + O_QUP;
    u16* wT_o   = wl + O_O;
    u16* wT_in  = wl + O_IN;
    u16* wT_out = wl + O_OUT;

    k_rms<<<Mm, 256, 0, stream>>>(h, 1024, norm1_w + l * 1024, xn, 1024);
    k_gemm<4, 64, 64><<<dim3(32, 12), 256, 0, stream>>>(xn, wT_dq, b_kv_down + l * 288,
                                                        b_q_down + l * 384, ckvq, 768, 1024);
    k_rms2<<<Mm, 256, 0, stream>>>(ckvq, kv_norm_w + l * 256, q_norm_w + l * 384,
                                   ckvn, qdn);
    // kv_up (N=2048,K=256) + q_up (N=1536,K=384) in one launch
    k_gemm_pair<<<dim3(32, 16, 2), 256, 0, stream>>>(
        ckvn, wT_kvup, b_kv_up + l * 2048, kv, 2048, 256, 16,
        qdn,  wT_qup,  b_q_up + l * 1536,  qf, 1536, 384, 12);
    k_buildkv<<<dim3(32, 32, 3), 256, 0, stream>>>(kv, ckvq, Kb, Vt);
    k_flash<<<dim3(8, 32), 256, 0, stream>>>(qf, Kb, Vt, attn);
    k_gemm<1, 64, 64><<<dim3(32, 16), 256, 0, stream>>>(attn, wT_o, b_o + l * 1024,
                                                        nullptr, h, 1024, 1024);
    k_rms<<<Mm, 256, 0, stream>>>(h, 1024, norm2_w + l * 1024, xn, 1024);
    k_gemm<3, 128, 128><<<dim3(16, 44), 256, 0, stream>>>(xn, wT_in, b_in + l * 5632,
                                                          nullptr, gate, 5632, 1024);
    k_gemm<1, 64, 64><<<dim3(32, 16), 256, 0, stream>>>(gate, wT_out, b_out + l * 1024,
                                                        nullptr, h, 1024, 2816);
  }

  k_rms<<<Mm, 256, 0, stream>>>(h, 1024, norm_f_w, xn, 1024);
  {
    // head weight conversion (aliases layer arena; all layer GEMMs are done)
    WJobs jbh;
    jbh.j[0] = { w_head, warena, 0, 1024, 32000, 0, 8000 };
    k_wcvt_batch<<<8000, 256, 0, stream>>>(jbh, 1, 8000, 0);
  }
  k_gemm<0, 128, 128><<<dim3(16, 250), 256, 0, stream>>>(xn, warena, b_head,
                                                         nullptr, (float*)d_out, 32000, 1024);
}